// Round 7
// baseline (16337.907 us; speedup 1.0000x reference)
//
#include <hip/hip_runtime.h>
#include <hip/hip_bf16.h>
#include <math.h>

typedef short bf16x8 __attribute__((ext_vector_type(8)));
typedef float f32x4 __attribute__((ext_vector_type(4)));
typedef unsigned short u16;

#define NT 64
#define NB 512
#define NS 256
#define NA 64
#define NBEL 1024

// d_out element offsets (f32 elements)
#define OUT_B      0
#define OUT_SPRI   33554432
#define OUT_MUPRI  41943040
#define OUT_STDPRI 50331648
#define OUT_SPOS   58720256
#define OUT_MUPOS  67108864
#define OUT_STDPOS 75497472

// flag kinds
#define KF_X 0
#define KF_BPRI 1
#define KF_HBO 2
#define KF_G 3
#define KF_SPRI 4
#define KF_B 5
#define KF_HB 6
#define KF_GH 7
#define KF_SMASK 8

__device__ __forceinline__ f32x4 mfma16(bf16x8 a, bf16x8 b, f32x4 c) {
  return __builtin_amdgcn_mfma_f32_16x16x32_bf16(a, b, c, 0, 0, 0);
}

__device__ __forceinline__ u16 f2bf(float f) {
  union { float f; unsigned u; } v; v.f = f;
  return (u16)((v.u + 0x7FFFu + ((v.u >> 16) & 1u)) >> 16);
}
__device__ __forceinline__ float bf2f(u16 h) {
  union { unsigned u; float f; } v; v.u = ((unsigned)h) << 16; return v.f;
}

__device__ __forceinline__ bf16x8 ld8bf(const u16* p) { return *(const bf16x8*)p; }

__device__ __forceinline__ bf16x8 cvt8(const float* p) {
  const float4 lo = *(const float4*)p;
  const float4 hi = *(const float4*)(p + 4);
  bf16x8 v;
  v[0] = (short)f2bf(lo.x); v[1] = (short)f2bf(lo.y);
  v[2] = (short)f2bf(lo.z); v[3] = (short)f2bf(lo.w);
  v[4] = (short)f2bf(hi.x); v[5] = (short)f2bf(hi.y);
  v[6] = (short)f2bf(hi.z); v[7] = (short)f2bf(hi.w);
  return v;
}

__device__ __forceinline__ float sigm(float x) { return 1.f / (1.f + __expf(-x)); }
__device__ __forceinline__ float softplus_(float x) {
  if (x > 20.f) return x;
  return log1pf(__expf(x));
}

#define ZACC(acc) { acc[0][0] = (f32x4){0.f,0.f,0.f,0.f}; acc[0][1] = (f32x4){0.f,0.f,0.f,0.f}; \
                    acc[1][0] = (f32x4){0.f,0.f,0.f,0.f}; acc[1][1] = (f32x4){0.f,0.f,0.f,0.f}; }

#define Q4(acc, a0v, a1v, b0v, b1v) \
  acc[0][0] = mfma16(a0v, b0v, acc[0][0]); \
  acc[0][1] = mfma16(a0v, b1v, acc[0][1]); \
  acc[1][0] = mfma16(a1v, b0v, acc[1][0]); \
  acc[1][1] = mfma16(a1v, b1v, acc[1][1]);

// 64x64 tile GEMM quadrant for one wave (bf16 A, bf16 B row-major [out_col][K])
__device__ __forceinline__ void gtile(f32x4 (&acc)[2][2],
    const u16* __restrict__ A, int lda, const u16* __restrict__ B, int ldb,
    int K, int r16, int kq) {
  const u16* A0 = A + r16 * lda + kq * 8;
  const u16* A1 = A0 + 16 * lda;
  const u16* B0 = B + (size_t)r16 * ldb + kq * 8;
  const u16* B1 = B0 + 16 * ldb;
#pragma unroll 4
  for (int k = 0; k < K; k += 32) {
    bf16x8 a0 = ld8bf(A0 + k), a1 = ld8bf(A1 + k);
    bf16x8 b0 = ld8bf(B0 + k), b1 = ld8bf(B1 + k);
    Q4(acc, a0, a1, b0, b1);
  }
}
__device__ __forceinline__ void gtileF(f32x4 (&acc)[2][2],
    const float* __restrict__ A, int lda, const u16* __restrict__ B, int ldb,
    int K, int r16, int kq) {
  const float* A0 = A + r16 * lda + kq * 8;
  const float* A1 = A0 + 16 * lda;
  const u16* B0 = B + (size_t)r16 * ldb + kq * 8;
  const u16* B1 = B0 + 16 * ldb;
#pragma unroll 2
  for (int k = 0; k < K; k += 32) {
    bf16x8 a0 = cvt8(A0 + k), a1 = cvt8(A1 + k);
    bf16x8 b0 = ld8bf(B0 + k), b1 = ld8bf(B1 + k);
    Q4(acc, a0, a1, b0, b1);
  }
}

// -------- flag sync (agent-scope release/acquire) --------
__device__ __forceinline__ void setflag(unsigned* f) {
  __syncthreads();
  if (threadIdx.x == 0)
    __hip_atomic_fetch_add(f, 1u, __ATOMIC_RELEASE, __HIP_MEMORY_SCOPE_AGENT);
}
__device__ __forceinline__ void waitflag(unsigned* f, unsigned target) {
  if (threadIdx.x == 0) {
    while (__hip_atomic_load(f, __ATOMIC_RELAXED, __HIP_MEMORY_SCOPE_AGENT) < target)
      __builtin_amdgcn_s_sleep(2);
    (void)__hip_atomic_load(f, __ATOMIC_ACQUIRE, __HIP_MEMORY_SCOPE_AGENT);
  }
  __syncthreads();
}

// -------- P0: weights f32 -> bf16 --------
__global__ __launch_bounds__(256) void cvt_weights_k(
    const float* __restrict__ wsa, const float* __restrict__ wih,
    const float* __restrict__ whh, const float* __restrict__ wbpri,
    const float* __restrict__ wspri, const float* __restrict__ wbpos,
    const float* __restrict__ wspos, u16* __restrict__ dst) {
  const int S0 = 327680;
  const int S1 = S0 + 3145728;
  const int S2 = S1 + 3145728;
  const int S3 = S2 + 1048576;
  const int S4 = S3 + 524288;
  const int S5 = S4 + 2097152;
  const int S6 = S5 + 524288;
  for (int i = blockIdx.x * blockDim.x + threadIdx.x; i < S6;
       i += gridDim.x * blockDim.x) {
    float v;
    if (i < S0) v = wsa[i];
    else if (i < S1) v = wih[i - S0];
    else if (i < S2) v = whh[i - S1];
    else if (i < S3) v = wbpri[i - S2];
    else if (i < S4) v = wspri[i - S3];
    else if (i < S5) v = wbpos[i - S4];
    else v = wspos[i - S5];
    dst[i] = f2bf(v);
  }
}

// -------- init for coop scan: per-XCD carries + flags --------
__global__ __launch_bounds__(256) void init_scan_k(
    const float* __restrict__ s0, const float* __restrict__ b0,
    const float* __restrict__ Mptr, u16* __restrict__ smask,
    u16* __restrict__ bbuf1, float* __restrict__ hf,
    unsigned* __restrict__ flags) {
  for (int i = blockIdx.x * blockDim.x + threadIdx.x; i < NB * NBEL;
       i += gridDim.x * blockDim.x) {
    const int row = i >> 10, c = i & 1023;
    const int xcd = row >> 6, lr = row & 63;
    const int o = xcd * 65536 + lr * 1024 + c;
    float b = b0[i];
    bbuf1[o] = f2bf(b);
    hf[o] = b;
    if (i < NB * NS) {
      const int row2 = i >> 8, c2 = i & 255;
      smask[(row2 >> 6) * 16384 + (row2 & 63) * 256 + c2] =
          f2bf(s0[i] * Mptr[row2]);
    }
    if (i < 8 * 66 * 10) flags[i] = 0;
  }
}

// ======================= cooperative whole-scan kernel =======================
struct SP {
  const float *Af, *Of, *Mp, *npri, *npos;
  const float *bsa, *bih, *bhh, *bbpri, *bspri, *bbpos, *bspos;
  const u16 *wsa, *wih, *whh, *wbpri, *wspri, *wbpos, *wspos;
  float *out;
  u16 *smask, *xbf, *bbuf0, *bbuf1, *gh, *hbo, *hb, *hpri;
  float *grzn, *hf;
  unsigned* flags;
};

__global__ void __launch_bounds__(256, 2) rssm_scan(SP p) {
  const int xcd = blockIdx.x & 7;
  const int s = blockIdx.x >> 3;           // slot 0..63 within XCD team
  const int rb = xcd * 64;                 // global batch row base
  const int l = threadIdx.x & 63, r16 = l & 15, kq = l >> 4;
  const int wid = threadIdx.x >> 6;
  const int lr0 = (wid >> 1) * 32;         // local row base of wave quadrant
  const int lc0 = (wid & 1) * 32;          // local col base of wave quadrant

  u16* smaskX = p.smask + xcd * 16384;
  u16* xbfX   = p.xbf   + xcd * 65536;
  float* grznX = p.grzn + xcd * 196608;
  u16* bbufX[2] = {p.bbuf0 + xcd * 65536, p.bbuf1 + xcd * 65536};
  float* hfX  = p.hf    + xcd * 65536;
  u16* ghX    = p.gh    + xcd * 196608;
  u16* hboX   = p.hbo   + xcd * 131072;    // [2][64][1024]
  u16* hbX    = p.hb    + xcd * 65536;
  u16* hpriX  = p.hpri  + xcd * 65536;
  unsigned* F = p.flags + xcd * 660;
#define FLG(t, k) (F + (t) * 10 + (k))

#define EPI(body) _Pragma("unroll") for (int i = 0; i < 2; ++i) \
  _Pragma("unroll") for (int j = 0; j < 2; ++j) \
  _Pragma("unroll") for (int q = 0; q < 4; ++q) { \
    const int lrow = lr0 + i * 16 + kq * 4 + q; \
    const int jc = j * 16 + r16; \
    body }

  // ---------------- prologue: hbO(0) | gh(0) ----------------
  if (s < 16) {
    const int colw = s * 64 + lc0;
    f32x4 acc[2][2]; ZACC(acc);
    gtileF(acc, p.Of + (size_t)(rb + lr0) * NBEL, NBEL,
           p.wbpos + (size_t)colw * 2048 + 1024, 2048, 1024, r16, kq);
    EPI({ hboX[lrow * 1024 + colw + jc] = f2bf(acc[i][j][q]); })
    setflag(FLG(0, KF_HBO));
  } else {
    const int colw = (s - 16) * 64 + lc0;  // 0..3071
    f32x4 acc[2][2]; ZACC(acc);
    gtile(acc, bbufX[1] + lr0 * 1024, 1024,
          p.whh + (size_t)colw * 1024, 1024, 1024, r16, kq);
    EPI({ const int c = colw + jc;
          ghX[lrow * 3072 + c] = f2bf(acc[i][j][q] + p.bhh[c]); })
    setflag(FLG(0, KF_GH));
  }

  for (int t = 0; t <= NT; ++t) {
    u16* bcur = bbufX[t & 1];
    const u16* bprev = bbufX[(t & 1) ^ 1];

    // ------------ P1: x(t) | bpri(t) | hbO(t+1) ------------
    if (s < 16) {
      if (t < NT) {
        if (t > 0) waitflag(FLG(t, KF_SMASK), 4);
        const int colw = s * 64 + lc0;
        f32x4 acc[2][2]; ZACC(acc);
        gtile(acc, smaskX + lr0 * 256, 256,
              p.wsa + (size_t)colw * 320, 320, 256, r16, kq);
        gtileF(acc, p.Af + (size_t)t * (NB * NA) + (size_t)(rb + lr0) * NA, NA,
               p.wsa + (size_t)colw * 320 + 256, 320, 64, r16, kq);
        EPI({ const int c = colw + jc;
              xbfX[lrow * 1024 + c] = f2bf(fmaxf(acc[i][j][q] + p.bsa[c], 0.f)); })
        setflag(FLG(t, KF_X));
      }
    } else if (s < 32) {
      if (t >= 1) {
        waitflag(FLG(t - 1, KF_B), 8);
        if (t >= 2) waitflag(FLG(t - 1, KF_SPRI), 4);
        const int colw = (s - 16) * 64 + lc0;
        f32x4 acc[2][2]; ZACC(acc);
        gtile(acc, bprev + lr0 * 1024, 1024,
              p.wbpri + (size_t)colw * 1024, 1024, 1024, r16, kq);
        EPI({ const int c = colw + jc;
              hpriX[lrow * 1024 + c] = f2bf(fmaxf(acc[i][j][q] + p.bbpri[c], 0.f)); })
        setflag(FLG(t, KF_BPRI));
      }
    } else if (s < 48) {
      if (t + 1 < NT) {
        if (t >= 1) waitflag(FLG(t - 1, KF_HB), 16);
        const int colw = (s - 32) * 64 + lc0;
        f32x4 acc[2][2]; ZACC(acc);
        gtileF(acc, p.Of + (size_t)(t + 1) * (NB * NBEL) + (size_t)(rb + lr0) * NBEL,
               NBEL, p.wbpos + (size_t)colw * 2048 + 1024, 2048, 1024, r16, kq);
        u16* dst = hboX + ((t + 1) & 1) * 65536;
        EPI({ dst[lrow * 1024 + colw + jc] = f2bf(acc[i][j][q]); })
        setflag(FLG(t + 1, KF_HBO));
      }
    }

    // ------------ P2a: gates(t) | spri(t-1) ------------
    if (s < 48) {
      if (t < NT) {
        waitflag(FLG(t, KF_X), 16);
        const int G = s / 16;
        const int colw = (s % 16) * 64 + lc0;
        f32x4 acc[2][2]; ZACC(acc);
        gtile(acc, xbfX + lr0 * 1024, 1024,
              p.wih + ((size_t)(G << 10) + colw) * 1024, 1024, 1024, r16, kq);
        EPI({ const int c = colw + jc;
              grznX[lrow * 3072 + (G << 10) + c] = acc[i][j][q] + p.bih[(G << 10) + c]; })
        setflag(FLG(t, KF_G));
      }
    } else if (s < 52) {
      if (t >= 1) {
        waitflag(FLG(t, KF_BPRI), 16);
        const int colw = (s - 48) * 64 + lc0;
        f32x4 am[2][2], ah[2][2]; ZACC(am); ZACC(ah);
        gtile(am, hpriX + lr0 * 1024, 1024,
              p.wspri + (size_t)colw * 1024, 1024, 1024, r16, kq);
        gtile(ah, hpriX + lr0 * 1024, 1024,
              p.wspri + (size_t)(256 + colw) * 1024, 1024, 1024, r16, kq);
        const int tt = t - 1;
        EPI({ const int c = colw + jc;
              const size_t idx = (size_t)tt * (NB * NS) + (size_t)(rb + lrow) * NS + c;
              const float mu = am[i][j][q] + p.bspri[c];
              const float hp = ah[i][j][q] + p.bspri[c + 256];
              const float sd = softplus_(hp) + 0.1f;
              p.out[OUT_SPRI + idx] = mu + sd * p.npri[idx];
              p.out[OUT_MUPRI + idx] = mu;
              p.out[OUT_STDPRI + idx] = sd; })
        setflag(FLG(t, KF_SPRI));
      }
    }

    // ------------ P2b: GRU epilogue -> bnew ------------
    if (s >= 56 && t < NT) {
      waitflag(FLG(t, KF_G), 48);
      waitflag(FLG(t, KF_GH), 48);
      const int ce = (s - 56) * 128;
      const int row = threadIdx.x >> 2;
      const int cbase = ce + (threadIdx.x & 3) * 32;
      const float* gi = grznX + row * 3072;
      const u16* ghr = ghX + row * 3072;
      float* hrow = hfX + row * 1024;
      u16* brow = bcur + row * 1024;
      float* orow = p.out + OUT_B + (size_t)t * (NB * NBEL) + (size_t)(rb + row) * NBEL;
#pragma unroll 8
      for (int ii = 0; ii < 32; ++ii) {
        const int c = cbase + ii;
        const float r = sigm(gi[c] + bf2f(ghr[c]));
        const float z = sigm(gi[c + 1024] + bf2f(ghr[c + 1024]));
        const float n = tanhf(gi[c + 2048] + r * bf2f(ghr[c + 2048]));
        const float h = hrow[c];
        const float bnew = (1.f - z) * n + z * h;
        hrow[c] = bnew;
        brow[c] = f2bf(bnew);
        orow[c] = bnew;
      }
      setflag(FLG(t, KF_B));
    }

    // ------------ P3: hbB(t) | gh(t+1) ------------
    if (s < 16) {
      if (t < NT) {
        waitflag(FLG(t, KF_B), 8);
        waitflag(FLG(t, KF_HBO), 16);
        const int colw = s * 64 + lc0;
        f32x4 acc[2][2]; ZACC(acc);
        gtile(acc, bcur + lr0 * 1024, 1024,
              p.wbpos + (size_t)colw * 2048, 2048, 1024, r16, kq);
        const u16* ho = hboX + (t & 1) * 65536;
        EPI({ const int c = colw + jc;
              const float v = acc[i][j][q] + bf2f(ho[lrow * 1024 + c]) + p.bbpos[c];
              hbX[lrow * 1024 + c] = f2bf(fmaxf(v, 0.f)); })
        setflag(FLG(t, KF_HB));
      }
    } else {
      if (t + 1 < NT) {
        waitflag(FLG(t, KF_B), 8);
        const int colw = (s - 16) * 64 + lc0;
        f32x4 acc[2][2]; ZACC(acc);
        gtile(acc, bcur + lr0 * 1024, 1024,
              p.whh + (size_t)colw * 1024, 1024, 1024, r16, kq);
        EPI({ const int c = colw + jc;
              ghX[lrow * 3072 + c] = f2bf(acc[i][j][q] + p.bhh[c]); })
        setflag(FLG(t + 1, KF_GH));
      }
    }

    // ------------ P4: spos(t) ------------
    if (s < 4 && t < NT) {
      waitflag(FLG(t, KF_HB), 16);
      const int colw = s * 64 + lc0;
      f32x4 am[2][2], ah[2][2]; ZACC(am); ZACC(ah);
      gtile(am, hbX + lr0 * 1024, 1024,
            p.wspos + (size_t)colw * 1024, 1024, 1024, r16, kq);
      gtile(ah, hbX + lr0 * 1024, 1024,
            p.wspos + (size_t)(256 + colw) * 1024, 1024, 1024, r16, kq);
      EPI({ const int c = colw + jc;
            const int rg = rb + lrow;
            const size_t idx = (size_t)t * (NB * NS) + (size_t)rg * NS + c;
            const float mu = am[i][j][q] + p.bspos[c];
            const float hq = ah[i][j][q] + p.bspos[c + 256];
            const float sd = softplus_(hq) + 0.1f;
            const float sq = mu + sd * p.npos[idx];
            p.out[OUT_SPOS + idx] = sq;
            p.out[OUT_MUPOS + idx] = mu;
            p.out[OUT_STDPOS + idx] = sd;
            const float mn = (t < NT - 1) ? p.Mp[(t + 1) * NB + rg] : 1.f;
            smaskX[lrow * 256 + c] = f2bf(sq * mn); })
      setflag(FLG(t + 1, KF_SMASK));
    }
  }
#undef FLG
#undef EPI
}

// ======================= fallback: proven R5 path =======================
__device__ __forceinline__ void red_write(float* L, f32x4 (&acc)[2][2], int l) {
  const int base = l * 16;
#pragma unroll
  for (int i = 0; i < 2; ++i)
#pragma unroll
    for (int j = 0; j < 2; ++j)
#pragma unroll
      for (int q = 0; q < 4; ++q)
        L[base + (i * 2 + j) * 4 + q] = acc[i][j][q];
}
__device__ __forceinline__ void red_add(const float* L, f32x4 (&acc)[2][2], int l) {
  const int base = l * 16;
#pragma unroll
  for (int i = 0; i < 2; ++i)
#pragma unroll
    for (int j = 0; j < 2; ++j)
#pragma unroll
      for (int q = 0; q < 4; ++q)
        acc[i][j][q] += L[base + (i * 2 + j) * 4 + q];
}

__global__ __launch_bounds__(256) void init_carry_k(
    const float* __restrict__ s0, const float* __restrict__ b0,
    const float* __restrict__ Mptr, u16* __restrict__ smask,
    u16* __restrict__ bbf0, float* __restrict__ hf) {
  for (int i = blockIdx.x * blockDim.x + threadIdx.x; i < NB * NBEL;
       i += gridDim.x * blockDim.x) {
    float b = b0[i];
    bbf0[i] = f2bf(b);
    hf[i] = b;
    if (i < NB * NS) {
      int row = i >> 8;
      smask[i] = f2bf(s0[i] * Mptr[row]);
    }
  }
}

__global__ __launch_bounds__(512, 2) void kA(
    const u16* __restrict__ smask, const float* __restrict__ Af,
    const u16* __restrict__ wsa, const float* __restrict__ bsa,
    u16* __restrict__ xbf, const float* __restrict__ Of,
    const u16* __restrict__ wbpos, float* __restrict__ hbO, int t) {
  __shared__ float lred[4][1024];
  const int l = threadIdx.x & 63, r16 = l & 15, kq = l >> 4;
  const int wid8 = threadIdx.x >> 6;
  const int wid = wid8 & 3, kh = wid8 >> 2;
  if (blockIdx.x < 128) {
    const int g = blockIdx.x, bm = g >> 4, bn = g & 15;
    const int row0 = bm * 64 + (wid >> 1) * 32;
    const int col0 = bn * 64 + (wid & 1) * 32;
    f32x4 acc[2][2]; ZACC(acc);
    const u16* A0 = smask + (row0 + r16) * NS + kq * 8;
    const u16* A1 = A0 + 16 * NS;
    const u16* B0 = wsa + (size_t)(col0 + r16) * 320 + kq * 8;
    const u16* B1 = B0 + 16 * 320;
    if (kh == 0) {
#pragma unroll
      for (int k = 0; k < 160; k += 32) {
        bf16x8 a0 = ld8bf(A0 + k), a1 = ld8bf(A1 + k);
        bf16x8 b0 = ld8bf(B0 + k), b1 = ld8bf(B1 + k);
        Q4(acc, a0, a1, b0, b1);
      }
    } else {
#pragma unroll
      for (int k = 160; k < 256; k += 32) {
        bf16x8 a0 = ld8bf(A0 + k), a1 = ld8bf(A1 + k);
        bf16x8 b0 = ld8bf(B0 + k), b1 = ld8bf(B1 + k);
        Q4(acc, a0, a1, b0, b1);
      }
      const float* F0 = Af + (size_t)t * (NB * NA) + (row0 + r16) * NA + kq * 8;
      const float* F1 = F0 + 16 * NA;
      const u16* C0 = wsa + (size_t)(col0 + r16) * 320 + 256 + kq * 8;
      const u16* C1 = C0 + 16 * 320;
#pragma unroll
      for (int k = 0; k < 64; k += 32) {
        bf16x8 a0 = cvt8(F0 + k), a1 = cvt8(F1 + k);
        bf16x8 b0 = ld8bf(C0 + k), b1 = ld8bf(C1 + k);
        Q4(acc, a0, a1, b0, b1);
      }
      red_write(lred[wid], acc, l);
    }
    __syncthreads();
    if (kh == 0) {
      red_add(lred[wid], acc, l);
#pragma unroll
      for (int i = 0; i < 2; ++i)
#pragma unroll
        for (int j = 0; j < 2; ++j)
#pragma unroll
          for (int q = 0; q < 4; ++q) {
            const int row = row0 + i * 16 + kq * 4 + q;
            const int col = col0 + j * 16 + r16;
            xbf[row * NBEL + col] = f2bf(fmaxf(acc[i][j][q] + bsa[col], 0.f));
          }
    }
  } else {
    const int g = blockIdx.x - 128, bm = g >> 4, bn = g & 15;
    const int row0 = bm * 64 + (wid >> 1) * 32;
    const int col0 = bn * 64 + (wid & 1) * 32;
    f32x4 acc[2][2]; ZACC(acc);
    const float* F0 = Of + (size_t)t * (NB * NBEL) + (row0 + r16) * NBEL + kh * 512 + kq * 8;
    const float* F1 = F0 + 16 * NBEL;
    const u16* B0 = wbpos + (size_t)(col0 + r16) * 2048 + 1024 + kh * 512 + kq * 8;
    const u16* B1 = B0 + 16 * 2048;
#pragma unroll 4
    for (int k = 0; k < 512; k += 32) {
      bf16x8 a0 = cvt8(F0 + k), a1 = cvt8(F1 + k);
      bf16x8 b0 = ld8bf(B0 + k), b1 = ld8bf(B1 + k);
      Q4(acc, a0, a1, b0, b1);
    }
    if (kh == 1) red_write(lred[wid], acc, l);
    __syncthreads();
    if (kh == 0) {
      red_add(lred[wid], acc, l);
#pragma unroll
      for (int i = 0; i < 2; ++i)
#pragma unroll
        for (int j = 0; j < 2; ++j)
#pragma unroll
          for (int q = 0; q < 4; ++q) {
            const int row = row0 + i * 16 + kq * 4 + q;
            const int col = col0 + j * 16 + r16;
            hbO[row * NBEL + col] = acc[i][j][q];
          }
    }
  }
}

__global__ __launch_bounds__(512, 2) void kB(
    const u16* __restrict__ xbf, const u16* __restrict__ bprev,
    const u16* __restrict__ wih, const u16* __restrict__ whh,
    const float* __restrict__ bih, const float* __restrict__ bhh,
    float* __restrict__ hf, u16* __restrict__ bcur, float* __restrict__ out,
    const u16* __restrict__ wbpri, const float* __restrict__ bbpri,
    u16* __restrict__ hpri, int t) {
  __shared__ float lred[4][3][1024];
  const int l = threadIdx.x & 63, r16 = l & 15, kq = l >> 4;
  const int wid8 = threadIdx.x >> 6;
  const int wid = wid8 & 3, kh = wid8 >> 2;
  if (blockIdx.x < 128) {
    if (t >= NT) return;
    const int g = blockIdx.x, bm = g >> 4, bn = g & 15;
    const int row0 = bm * 64 + (wid >> 1) * 32;
    const int col0 = bn * 64 + (wid & 1) * 32;
    f32x4 ar[2][2], az[2][2], an[2][2];
    ZACC(ar); ZACC(az); ZACC(an);
    const u16* Asrc = (kh == 0) ? xbf : bprev;
    const u16* W = (kh == 0) ? wih : whh;
    const u16* A0 = Asrc + (row0 + r16) * NBEL + kq * 8;
    const u16* A1 = A0 + 16 * NBEL;
    const u16* Br0 = W + (size_t)(col0 + r16) * NBEL + kq * 8;
    const u16* Br1 = Br0 + 16 * NBEL;
    const u16* Bz0 = W + (size_t)(col0 + 1024 + r16) * NBEL + kq * 8;
    const u16* Bz1 = Bz0 + 16 * NBEL;
    const u16* Bn0 = W + (size_t)(col0 + 2048 + r16) * NBEL + kq * 8;
    const u16* Bn1 = Bn0 + 16 * NBEL;
#pragma unroll 4
    for (int k = 0; k < NBEL; k += 32) {
      bf16x8 a0 = ld8bf(A0 + k), a1 = ld8bf(A1 + k);
      bf16x8 b0 = ld8bf(Br0 + k), b1 = ld8bf(Br1 + k);
      Q4(ar, a0, a1, b0, b1);
      bf16x8 c0 = ld8bf(Bz0 + k), c1 = ld8bf(Bz1 + k);
      Q4(az, a0, a1, c0, c1);
      bf16x8 d0 = ld8bf(Bn0 + k), d1 = ld8bf(Bn1 + k);
      Q4(an, a0, a1, d0, d1);
    }
    if (kh == 1) {
      red_write(&lred[wid][0][0], ar, l);
      red_write(&lred[wid][1][0], az, l);
      red_write(&lred[wid][2][0], an, l);
    }
    __syncthreads();
    if (kh == 0) {
      const int base = l * 16;
#pragma unroll
      for (int i = 0; i < 2; ++i)
#pragma unroll
        for (int j = 0; j < 2; ++j)
#pragma unroll
          for (int q = 0; q < 4; ++q) {
            const int row = row0 + i * 16 + kq * 4 + q;
            const int c = col0 + j * 16 + r16;
            const int li = base + (i * 2 + j) * 4 + q;
            const float r = sigm(ar[i][j][q] + bih[c] + lred[wid][0][li] + bhh[c]);
            const float z = sigm(az[i][j][q] + bih[c + 1024] + lred[wid][1][li] + bhh[c + 1024]);
            const float n = tanhf(an[i][j][q] + bih[c + 2048] +
                                  r * (lred[wid][2][li] + bhh[c + 2048]));
            const float h = hf[row * NBEL + c];
            const float bnew = (1.f - z) * n + z * h;
            hf[row * NBEL + c] = bnew;
            bcur[row * NBEL + c] = f2bf(bnew);
            out[OUT_B + (size_t)t * (NB * NBEL) + row * NBEL + c] = bnew;
          }
    }
  } else {
    if (t < 1) return;
    const int g = blockIdx.x - 128, bm = g >> 4, bn = g & 15;
    const int row0 = bm * 64 + (wid >> 1) * 32;
    const int col0 = bn * 64 + (wid & 1) * 32;
    f32x4 acc[2][2]; ZACC(acc);
    const u16* A0 = bprev + (row0 + r16) * NBEL + kh * 512 + kq * 8;
    const u16* A1 = A0 + 16 * NBEL;
    const u16* B0 = wbpri + (size_t)(col0 + r16) * NBEL + kh * 512 + kq * 8;
    const u16* B1 = B0 + 16 * NBEL;
#pragma unroll 4
    for (int k = 0; k < 512; k += 32) {
      bf16x8 a0 = ld8bf(A0 + k), a1 = ld8bf(A1 + k);
      bf16x8 b0 = ld8bf(B0 + k), b1 = ld8bf(B1 + k);
      Q4(acc, a0, a1, b0, b1);
    }
    if (kh == 1) red_write(&lred[wid][0][0], acc, l);
    __syncthreads();
    if (kh == 0) {
      red_add(&lred[wid][0][0], acc, l);
#pragma unroll
      for (int i = 0; i < 2; ++i)
#pragma unroll
        for (int j = 0; j < 2; ++j)
#pragma unroll
          for (int q = 0; q < 4; ++q) {
            const int row = row0 + i * 16 + kq * 4 + q;
            const int col = col0 + j * 16 + r16;
            hpri[row * NBEL + col] = f2bf(fmaxf(acc[i][j][q] + bbpri[col], 0.f));
          }
    }
  }
}

__global__ __launch_bounds__(512, 2) void kC(
    const u16* __restrict__ bcur, const u16* __restrict__ wbpos,
    const float* __restrict__ bbpos, const float* __restrict__ hbO,
    u16* __restrict__ hbbf,
    const u16* __restrict__ hpri, const u16* __restrict__ wspri,
    const float* __restrict__ bspri, const float* __restrict__ npri,
    float* __restrict__ out, int t) {
  __shared__ float lred[4][2][1024];
  const int l = threadIdx.x & 63, r16 = l & 15, kq = l >> 4;
  const int wid8 = threadIdx.x >> 6;
  const int wid = wid8 & 3, kh = wid8 >> 2;
  if (blockIdx.x < 128) {
    if (t >= NT) return;
    const int g = blockIdx.x, bm = g >> 4, bn = g & 15;
    const int row0 = bm * 64 + (wid >> 1) * 32;
    const int col0 = bn * 64 + (wid & 1) * 32;
    f32x4 acc[2][2]; ZACC(acc);
    const u16* A0 = bcur + (row0 + r16) * NBEL + kh * 512 + kq * 8;
    const u16* A1 = A0 + 16 * NBEL;
    const u16* B0 = wbpos + (size_t)(col0 + r16) * 2048 + kh * 512 + kq * 8;
    const u16* B1 = B0 + 16 * 2048;
#pragma unroll 4
    for (int k = 0; k < 512; k += 32) {
      bf16x8 a0 = ld8bf(A0 + k), a1 = ld8bf(A1 + k);
      bf16x8 b0 = ld8bf(B0 + k), b1 = ld8bf(B1 + k);
      Q4(acc, a0, a1, b0, b1);
    }
    if (kh == 1) red_write(&lred[wid][0][0], acc, l);
    __syncthreads();
    if (kh == 0) {
      red_add(&lred[wid][0][0], acc, l);
#pragma unroll
      for (int i = 0; i < 2; ++i)
#pragma unroll
        for (int j = 0; j < 2; ++j)
#pragma unroll
          for (int q = 0; q < 4; ++q) {
            const int row = row0 + i * 16 + kq * 4 + q;
            const int col = col0 + j * 16 + r16;
            const float v = acc[i][j][q] + hbO[row * NBEL + col] + bbpos[col];
            hbbf[row * NBEL + col] = f2bf(fmaxf(v, 0.f));
          }
    }
  } else {
    if (t < 1) return;
    const int g = blockIdx.x - 128, bm = g >> 2, bn = g & 3;
    const int row0 = bm * 64 + (wid >> 1) * 32;
    const int c0 = bn * 64 + (wid & 1) * 32;
    f32x4 am[2][2], ah[2][2];
    ZACC(am); ZACC(ah);
    const u16* A0 = hpri + (row0 + r16) * NBEL + kh * 512 + kq * 8;
    const u16* A1 = A0 + 16 * NBEL;
    const u16* Bm0 = wspri + (size_t)(c0 + r16) * NBEL + kh * 512 + kq * 8;
    const u16* Bm1 = Bm0 + 16 * NBEL;
    const u16* Bh0 = wspri + (size_t)(c0 + 256 + r16) * NBEL + kh * 512 + kq * 8;
    const u16* Bh1 = Bh0 + 16 * NBEL;
#pragma unroll 4
    for (int k = 0; k < 512; k += 32) {
      bf16x8 a0 = ld8bf(A0 + k), a1 = ld8bf(A1 + k);
      bf16x8 m0 = ld8bf(Bm0 + k), m1 = ld8bf(Bm1 + k);
      Q4(am, a0, a1, m0, m1);
      bf16x8 h0 = ld8bf(Bh0 + k), h1 = ld8bf(Bh1 + k);
      Q4(ah, a0, a1, h0, h1);
    }
    if (kh == 1) {
      red_write(&lred[wid][0][0], am, l);
      red_write(&lred[wid][1][0], ah, l);
    }
    __syncthreads();
    if (kh == 0) {
      red_add(&lred[wid][0][0], am, l);
      red_add(&lred[wid][1][0], ah, l);
      const int tt = t - 1;
#pragma unroll
      for (int i = 0; i < 2; ++i)
#pragma unroll
        for (int j = 0; j < 2; ++j)
#pragma unroll
          for (int q = 0; q < 4; ++q) {
            const int row = row0 + i * 16 + kq * 4 + q;
            const int c = c0 + j * 16 + r16;
            const size_t idx = (size_t)tt * (NB * NS) + row * NS + c;
            const float mu = am[i][j][q] + bspri[c];
            const float hp = ah[i][j][q] + bspri[c + 256];
            const float sd = softplus_(hp) + 0.1f;
            out[OUT_SPRI + idx] = mu + sd * npri[idx];
            out[OUT_MUPRI + idx] = mu;
            out[OUT_STDPRI + idx] = sd;
          }
    }
  }
}

__global__ __launch_bounds__(512, 2) void kD(
    const u16* __restrict__ hbbf, const u16* __restrict__ wspos,
    const float* __restrict__ bspos, const float* __restrict__ npos,
    const float* __restrict__ Mptr, float* __restrict__ out,
    u16* __restrict__ smask, int t) {
  __shared__ float lred[4][2][1024];
  const int l = threadIdx.x & 63, r16 = l & 15, kq = l >> 4;
  const int wid8 = threadIdx.x >> 6;
  const int wid = wid8 & 3, kh = wid8 >> 2;
  const int g = blockIdx.x, bm = g >> 2, bn = g & 3;
  const int row0 = bm * 64 + (wid >> 1) * 32;
  const int c0 = bn * 64 + (wid & 1) * 32;
  f32x4 am[2][2], ah[2][2];
  ZACC(am); ZACC(ah);
  const u16* A0 = hbbf + (row0 + r16) * NBEL + kh * 512 + kq * 8;
  const u16* A1 = A0 + 16 * NBEL;
  const u16* Bm0 = wspos + (size_t)(c0 + r16) * NBEL + kh * 512 + kq * 8;
  const u16* Bm1 = Bm0 + 16 * NBEL;
  const u16* Bh0 = wspos + (size_t)(c0 + 256 + r16) * NBEL + kh * 512 + kq * 8;
  const u16* Bh1 = Bh0 + 16 * NBEL;
#pragma unroll 4
  for (int k = 0; k < 512; k += 32) {
    bf16x8 a0 = ld8bf(A0 + k), a1 = ld8bf(A1 + k);
    bf16x8 m0 = ld8bf(Bm0 + k), m1 = ld8bf(Bm1 + k);
    Q4(am, a0, a1, m0, m1);
    bf16x8 h0 = ld8bf(Bh0 + k), h1 = ld8bf(Bh1 + k);
    Q4(ah, a0, a1, h0, h1);
  }
  if (kh == 1) {
    red_write(&lred[wid][0][0], am, l);
    red_write(&lred[wid][1][0], ah, l);
  }
  __syncthreads();
  if (kh == 0) {
    red_add(&lred[wid][0][0], am, l);
    red_add(&lred[wid][1][0], ah, l);
#pragma unroll
    for (int i = 0; i < 2; ++i)
#pragma unroll
      for (int j = 0; j < 2; ++j)
#pragma unroll
        for (int q = 0; q < 4; ++q) {
          const int row = row0 + i * 16 + kq * 4 + q;
          const int c = c0 + j * 16 + r16;
          const float mu = am[i][j][q] + bspos[c];
          const float hq = ah[i][j][q] + bspos[c + 256];
          const float sd = softplus_(hq) + 0.1f;
          const size_t idx = (size_t)t * (NB * NS) + row * NS + c;
          const float sq = mu + sd * npos[idx];
          out[OUT_SPOS + idx] = sq;
          out[OUT_MUPOS + idx] = mu;
          out[OUT_STDPOS + idx] = sd;
          const float mn = (t < NT - 1) ? Mptr[(t + 1) * NB + row] : 1.f;
          smask[row * NS + c] = f2bf(sq * mn);
        }
  }
}

extern "C" void kernel_launch(void* const* d_in, const int* in_sizes, int n_in,
                              void* d_out, int out_size, void* d_ws, size_t ws_size,
                              hipStream_t stream) {
  const float* s0 = (const float*)d_in[0];
  const float* Af = (const float*)d_in[1];
  const float* b0 = (const float*)d_in[2];
  const float* Of = (const float*)d_in[3];
  const float* Mp = (const float*)d_in[4];
  const float* npri = (const float*)d_in[5];
  const float* npos = (const float*)d_in[6];
  const float* Wsa = (const float*)d_in[7];
  const float* bsa = (const float*)d_in[8];
  const float* Wih = (const float*)d_in[9];
  const float* bih = (const float*)d_in[10];
  const float* Whh = (const float*)d_in[11];
  const float* bhh = (const float*)d_in[12];
  const float* Wbpri = (const float*)d_in[13];
  const float* bbpri = (const float*)d_in[14];
  const float* Wspri = (const float*)d_in[15];
  const float* bspri = (const float*)d_in[16];
  const float* Wbpos = (const float*)d_in[17];
  const float* bbpos = (const float*)d_in[18];
  const float* Wspos = (const float*)d_in[19];
  const float* bspos = (const float*)d_in[20];

  float* out = (float*)d_out;
  char* ws = (char*)d_ws;
  u16* wbase   = (u16*)ws;
  u16* wsa_b   = wbase;
  u16* wih_b   = wbase + 327680;
  u16* whh_b   = wbase + 3473408;
  u16* wbpri_b = wbase + 6619136;
  u16* wspri_b = wbase + 7667712;
  u16* wbpos_b = wbase + 8192000;
  u16* wspos_b = wbase + 10289152;
  // weights end at byte 21,626,880

  // coop-scan layout
  unsigned* flags = (unsigned*)(ws + 21626880);   // 8*66*10 u32 (pad to 32KB)
  u16*   smaskC = (u16*)  (ws + 21659648);  // [8][64][256]
  u16*   xbfC   = (u16*)  (ws + 21921792);  // [8][64][1024]
  float* grznC  = (float*)(ws + 22970368);  // [8][64][3072]
  u16*   bbuf0C = (u16*)  (ws + 29261824);  // [8][64][1024]
  u16*   bbuf1C = (u16*)  (ws + 30310400);  // [8][64][1024]
  float* hfC    = (float*)(ws + 31358976);  // [8][64][1024]
  u16*   ghC    = (u16*)  (ws + 33456128);  // [8][64][3072]
  u16*   hboC   = (u16*)  (ws + 36601856);  // [8][2][64][1024]
  u16*   hbC    = (u16*)  (ws + 38699008);  // [8][64][1024]
  u16*   hpriC  = (u16*)  (ws + 39747584);  // [8][64][1024]
  // coop end: 40,796,160 bytes

  cvt_weights_k<<<2048, 256, 0, stream>>>(Wsa, Wih, Whh, Wbpri, Wspri, Wbpos,
                                          Wspos, wbase);
  init_scan_k<<<2048, 256, 0, stream>>>(s0, b0, Mp, smaskC, bbuf1C, hfC, flags);

  SP p;
  p.Af = Af; p.Of = Of; p.Mp = Mp; p.npri = npri; p.npos = npos;
  p.bsa = bsa; p.bih = bih; p.bhh = bhh; p.bbpri = bbpri; p.bspri = bspri;
  p.bbpos = bbpos; p.bspos = bspos;
  p.wsa = wsa_b; p.wih = wih_b; p.whh = whh_b; p.wbpri = wbpri_b;
  p.wspri = wspri_b; p.wbpos = wbpos_b; p.wspos = wspos_b;
  p.out = out;
  p.smask = smaskC; p.xbf = xbfC; p.bbuf0 = bbuf0C; p.bbuf1 = bbuf1C;
  p.gh = ghC; p.hbo = hboC; p.hb = hbC; p.hpri = hpriC;
  p.grzn = grznC; p.hf = hfC;
  p.flags = flags;

  void* args[] = {(void*)&p};
  hipError_t err = hipLaunchCooperativeKernel(
      reinterpret_cast<const void*>(&rssm_scan), dim3(512), dim3(256),
      args, 0, stream);
  if (err == hipSuccess) return;

  // -------- fallback: proven R5 multi-kernel path --------
  u16*   smask = (u16*)  (ws + 21626880);
  u16*   bbf0  = (u16*)  (ws + 21889024);
  u16*   bbf1  = (u16*)  (ws + 22937600);
  float* hf    = (float*)(ws + 23986176);
  u16*   xbf   = (u16*)  (ws + 26083328);
  float* hbO   = (float*)(ws + 27131904);
  u16*   hbbf  = (u16*)  (ws + 29229056);
  u16*   hpri  = (u16*)  (ws + 30277632);

  init_carry_k<<<2048, 256, 0, stream>>>(s0, b0, Mp, smask, bbf0, hf);
  for (int t = 0; t < NT; ++t) {
    const u16* bprev = (t & 1) ? bbf1 : bbf0;
    u16* bcur = (t & 1) ? bbf0 : bbf1;
    kA<<<256, 512, 0, stream>>>(smask, Af, wsa_b, bsa, xbf, Of, wbpos_b, hbO, t);
    kB<<<256, 512, 0, stream>>>(xbf, bprev, wih_b, whh_b, bih, bhh, hf, bcur,
                                out, wbpri_b, bbpri, hpri, t);
    kC<<<160, 512, 0, stream>>>(bcur, wbpos_b, bbpos, hbO, hbbf,
                                hpri, wspri_b, bspri, npri, out, t);
    kD<<<32, 512, 0, stream>>>(hbbf, wspos_b, bspos, npos, Mp, out, smask, t);
  }
  {
    const int t = NT;
    const u16* bprev = (t & 1) ? bbf1 : bbf0;
    u16* bcur = (t & 1) ? bbf0 : bbf1;
    kB<<<256, 512, 0, stream>>>(xbf, bprev, wih_b, whh_b, bih, bhh, hf, bcur,
                                out, wbpri_b, bbpri, hpri, t);
    kC<<<160, 512, 0, stream>>>(bcur, wbpos_b, bbpos, hbO, hbbf,
                                hpri, wspri_b, bspri, npri, out, t);
  }
}

// Round 8
// 14460.930 us; speedup vs baseline: 1.1298x; 1.1298x over previous
//
#include <hip/hip_runtime.h>
#include <hip/hip_bf16.h>
#include <math.h>

typedef short bf16x8 __attribute__((ext_vector_type(8)));
typedef float f32x4 __attribute__((ext_vector_type(4)));
typedef unsigned short u16;

#define NT 64
#define NB 512
#define NS 256
#define NA 64
#define NBEL 1024

// d_out element offsets (f32 elements)
#define OUT_B      0
#define OUT_SPRI   33554432
#define OUT_MUPRI  41943040
#define OUT_STDPRI 50331648
#define OUT_SPOS   58720256
#define OUT_MUPOS  67108864
#define OUT_STDPOS 75497472

// global flag kinds: X=0 B=1 BPRI=2 SPRI=3 HB=4 SMASK=5 ; local: HBO=0 GI=1 GH=2

__device__ __forceinline__ f32x4 mfma16(bf16x8 a, bf16x8 b, f32x4 c) {
  return __builtin_amdgcn_mfma_f32_16x16x32_bf16(a, b, c, 0, 0, 0);
}

__device__ __forceinline__ u16 f2bf(float f) {
  union { float f; unsigned u; } v; v.f = f;
  return (u16)((v.u + 0x7FFFu + ((v.u >> 16) & 1u)) >> 16);
}
__device__ __forceinline__ float bf2f(u16 h) {
  union { unsigned u; float f; } v; v.u = ((unsigned)h) << 16; return v.f;
}

__device__ __forceinline__ bf16x8 ld8bf(const u16* p) { return *(const bf16x8*)p; }

__device__ __forceinline__ bf16x8 cvt8(const float* p) {
  const float4 lo = *(const float4*)p;
  const float4 hi = *(const float4*)(p + 4);
  bf16x8 v;
  v[0] = (short)f2bf(lo.x); v[1] = (short)f2bf(lo.y);
  v[2] = (short)f2bf(lo.z); v[3] = (short)f2bf(lo.w);
  v[4] = (short)f2bf(hi.x); v[5] = (short)f2bf(hi.y);
  v[6] = (short)f2bf(hi.z); v[7] = (short)f2bf(hi.w);
  return v;
}

__device__ __forceinline__ float sigm(float x) { return 1.f / (1.f + __expf(-x)); }
__device__ __forceinline__ float softplus_(float x) {
  if (x > 20.f) return x;
  return log1pf(__expf(x));
}

#define ZACC(acc) { acc[0][0] = (f32x4){0.f,0.f,0.f,0.f}; acc[0][1] = (f32x4){0.f,0.f,0.f,0.f}; \
                    acc[1][0] = (f32x4){0.f,0.f,0.f,0.f}; acc[1][1] = (f32x4){0.f,0.f,0.f,0.f}; }

#define Q4(acc, a0v, a1v, b0v, b1v) \
  acc[0][0] = mfma16(a0v, b0v, acc[0][0]); \
  acc[0][1] = mfma16(a0v, b1v, acc[0][1]); \
  acc[1][0] = mfma16(a1v, b0v, acc[1][0]); \
  acc[1][1] = mfma16(a1v, b1v, acc[1][1]);

__device__ __forceinline__ void gtile(f32x4 (&acc)[2][2],
    const u16* __restrict__ A, int lda, const u16* __restrict__ B, int ldb,
    int K, int r16, int kq) {
  const u16* A0 = A + r16 * lda + kq * 8;
  const u16* A1 = A0 + 16 * lda;
  const u16* B0 = B + (size_t)r16 * ldb + kq * 8;
  const u16* B1 = B0 + 16 * ldb;
#pragma unroll 4
  for (int k = 0; k < K; k += 32) {
    bf16x8 a0 = ld8bf(A0 + k), a1 = ld8bf(A1 + k);
    bf16x8 b0 = ld8bf(B0 + k), b1 = ld8bf(B1 + k);
    Q4(acc, a0, a1, b0, b1);
  }
}
__device__ __forceinline__ void gtileF(f32x4 (&acc)[2][2],
    const float* __restrict__ A, int lda, const u16* __restrict__ B, int ldb,
    int K, int r16, int kq) {
  const float* A0 = A + r16 * lda + kq * 8;
  const float* A1 = A0 + 16 * lda;
  const u16* B0 = B + (size_t)r16 * ldb + kq * 8;
  const u16* B1 = B0 + 16 * ldb;
#pragma unroll 2
  for (int k = 0; k < K; k += 32) {
    bf16x8 a0 = cvt8(A0 + k), a1 = cvt8(A1 + k);
    bf16x8 b0 = ld8bf(B0 + k), b1 = ld8bf(B1 + k);
    Q4(acc, a0, a1, b0, b1);
  }
}

__device__ __forceinline__ void setflag(unsigned* f) {
  __syncthreads();
  if (threadIdx.x == 0)
    __hip_atomic_fetch_add(f, 1u, __ATOMIC_RELEASE, __HIP_MEMORY_SCOPE_AGENT);
}
__device__ __forceinline__ void waitflag(unsigned* f, unsigned target) {
  if (threadIdx.x == 0) {
    while (__hip_atomic_load(f, __ATOMIC_RELAXED, __HIP_MEMORY_SCOPE_AGENT) < target)
      __builtin_amdgcn_s_sleep(2);
    (void)__hip_atomic_load(f, __ATOMIC_ACQUIRE, __HIP_MEMORY_SCOPE_AGENT);
  }
  __syncthreads();
}

// -------- P0: weights f32 -> bf16 --------
__global__ __launch_bounds__(256) void cvt_weights_k(
    const float* __restrict__ wsa, const float* __restrict__ wih,
    const float* __restrict__ whh, const float* __restrict__ wbpri,
    const float* __restrict__ wspri, const float* __restrict__ wbpos,
    const float* __restrict__ wspos, u16* __restrict__ dst) {
  const int S0 = 327680;
  const int S1 = S0 + 3145728;
  const int S2 = S1 + 3145728;
  const int S3 = S2 + 1048576;
  const int S4 = S3 + 524288;
  const int S5 = S4 + 2097152;
  const int S6 = S5 + 524288;
  for (int i = blockIdx.x * blockDim.x + threadIdx.x; i < S6;
       i += gridDim.x * blockDim.x) {
    float v;
    if (i < S0) v = wsa[i];
    else if (i < S1) v = wih[i - S0];
    else if (i < S2) v = whh[i - S1];
    else if (i < S3) v = wbpri[i - S2];
    else if (i < S4) v = wspri[i - S3];
    else if (i < S5) v = wbpos[i - S4];
    else v = wspos[i - S5];
    dst[i] = f2bf(v);
  }
}

// -------- init for column-partitioned scan --------
__global__ __launch_bounds__(256) void init2_k(
    const float* __restrict__ s0, const float* __restrict__ b0,
    const float* __restrict__ Mptr, u16* __restrict__ smaskg,
    u16* __restrict__ bn1, float* __restrict__ hfX,
    unsigned* __restrict__ flags) {
  for (int i = blockIdx.x * blockDim.x + threadIdx.x; i < NB * NBEL;
       i += gridDim.x * blockDim.x) {
    const int row = i >> 10, c = i & 1023;
    const float b = b0[i];
    bn1[i] = f2bf(b);
    hfX[(((size_t)(c >> 7)) * 512 + row) * 128 + (c & 127)] = b;
    if (i < NB * NS) {
      const int r2 = i >> 8;
      smaskg[i] = f2bf(s0[i] * Mptr[r2]);
    }
    if (i < 2040) {  // 6*68 global + 8*3*68 local counters
      unsigned v = 0;
      if (i < 408) {
        const int kind = i / 68, tt = i % 68;
        if (tt == 0 && kind == 1) v = 128;          // B[0]: b0 ready
        else if (tt == 0 && (kind == 3 || kind == 5)) v = 64;  // SPRI[0], SMASK[0]
      }
      flags[i] = v;
    }
  }
}

// ======================= column-partitioned persistent scan =======================
struct SP2 {
  const float *Af, *Of, *Mp, *npri, *npos;
  const float *bsa, *bih, *bhh, *bbpri, *bspri, *bbpos, *bspos;
  const u16 *wsa, *wih, *whh, *wbpri, *wspri, *wbpos, *wspos;
  float *out;
  u16 *smaskg, *xg, *bn0, *bn1, *hbg, *hprig, *hbo, *ghX;
  float *giX, *hfX;
  unsigned *flagsG, *flagsL;
};

__global__ void __launch_bounds__(256, 2) rssm_scan2(SP2 p) {
  const int slot = blockIdx.x >> 3;   // 0..63 team slot
  const int xcd  = blockIdx.x & 7;    // column-slice owner
  const int l = threadIdx.x & 63, r16 = l & 15, kq = l >> 4;
  const int wid = threadIdx.x >> 6;
  const int qr = (wid >> 1) * 32, qc = (wid & 1) * 32;
  __shared__ float sp_lds[2][64][32];

#define FGp(k, tt) (p.flagsG + (k) * 68 + (tt))
#define FLp(k, tt) (p.flagsL + (xcd * 3 + (k)) * 68 + (tt))

  // ---- prologue: hbO(0) by slots 16..31 ----
  if (slot >= 16 && slot < 32) {
    const int s = slot - 16;
    const int row0 = (s >> 1) * 64 + qr;
    const int cl0 = (s & 1) * 64 + qc;
    const int colw = xcd * 128 + cl0;
    f32x4 acc[2][2]; ZACC(acc);
    gtileF(acc, p.Of + (size_t)row0 * NBEL, NBEL,
           p.wbpos + (size_t)colw * 2048 + 1024, 2048, 1024, r16, kq);
    u16* dst = p.hbo + ((size_t)xcd * 2 + 0) * 65536;
#pragma unroll
    for (int ii = 0; ii < 2; ++ii)
#pragma unroll
      for (int jj = 0; jj < 2; ++jj)
#pragma unroll
        for (int qq = 0; qq < 4; ++qq) {
          const int row = row0 + ii * 16 + kq * 4 + qq;
          dst[row * 128 + cl0 + jj * 16 + r16] = f2bf(acc[ii][jj][qq]);
        }
    setflag(FLp(0, 0));
  }

  for (int t = 0; t <= NT; ++t) {
    u16* bcur = (t & 1) ? p.bn1 : p.bn0;
    const u16* bprev = (t & 1) ? p.bn0 : p.bn1;

    // ---- Ph1: x(t) [0..15] | hbO(t+1) [16..31] ----
    if (slot < 16) {
      if (t < NT) {
        waitflag(FGp(5, t), 64);
        const int s = slot;
        const int row0 = (s >> 1) * 64 + qr;
        const int cl0 = (s & 1) * 64 + qc;
        const int colw = xcd * 128 + cl0;
        f32x4 acc[2][2]; ZACC(acc);
        gtile(acc, p.smaskg + row0 * 256, 256,
              p.wsa + (size_t)colw * 320, 320, 256, r16, kq);
        gtileF(acc, p.Af + (size_t)t * (NB * NA) + (size_t)row0 * NA, NA,
               p.wsa + (size_t)colw * 320 + 256, 320, 64, r16, kq);
#pragma unroll
        for (int ii = 0; ii < 2; ++ii)
#pragma unroll
          for (int jj = 0; jj < 2; ++jj)
#pragma unroll
            for (int qq = 0; qq < 4; ++qq) {
              const int row = row0 + ii * 16 + kq * 4 + qq;
              const int col = colw + jj * 16 + r16;
              p.xg[row * 1024 + col] = f2bf(fmaxf(acc[ii][jj][qq] + p.bsa[col], 0.f));
            }
        setflag(FGp(0, t));
      }
    } else if (slot < 32) {
      if (t + 1 < NT) {
        if (t >= 1) waitflag(FGp(4, t - 1), 128);
        const int s = slot - 16;
        const int row0 = (s >> 1) * 64 + qr;
        const int cl0 = (s & 1) * 64 + qc;
        const int colw = xcd * 128 + cl0;
        f32x4 acc[2][2]; ZACC(acc);
        gtileF(acc, p.Of + (size_t)(t + 1) * (NB * NBEL) + (size_t)row0 * NBEL, NBEL,
               p.wbpos + (size_t)colw * 2048 + 1024, 2048, 1024, r16, kq);
        u16* dst = p.hbo + ((size_t)xcd * 2 + ((t + 1) & 1)) * 65536;
#pragma unroll
        for (int ii = 0; ii < 2; ++ii)
#pragma unroll
          for (int jj = 0; jj < 2; ++jj)
#pragma unroll
            for (int qq = 0; qq < 4; ++qq) {
              const int row = row0 + ii * 16 + kq * 4 + qq;
              dst[row * 128 + cl0 + jj * 16 + r16] = f2bf(acc[ii][jj][qq]);
            }
        setflag(FLp(0, t + 1));
      }
    }

    // ---- Ph2: gh (slots 0..47) | gi (slots 48..63 + second on 0..31) ----
    if (t < NT) {
      if (slot < 48) {
        waitflag(FGp(1, t), 128);
        const int G = slot >> 4, s = slot & 15;
        const int row0 = (s >> 1) * 64 + qr;
        const int cl0 = (s & 1) * 64 + qc;
        const int colw = G * 1024 + xcd * 128 + cl0;
        f32x4 acc[2][2]; ZACC(acc);
        gtile(acc, bprev + row0 * 1024, 1024,
              p.whh + (size_t)colw * 1024, 1024, 1024, r16, kq);
#pragma unroll
        for (int ii = 0; ii < 2; ++ii)
#pragma unroll
          for (int jj = 0; jj < 2; ++jj)
#pragma unroll
            for (int qq = 0; qq < 4; ++qq) {
              const int row = row0 + ii * 16 + kq * 4 + qq;
              const int jc = jj * 16 + r16;
              p.ghX[((size_t)xcd * 512 + row) * 384 + G * 128 + cl0 + jc] =
                  f2bf(acc[ii][jj][qq] + p.bhh[colw + jc]);
            }
        setflag(FLp(2, t));
      } else {
        waitflag(FGp(0, t), 128);
        const int i0 = slot - 48;
        const int G = i0 >> 4, s = i0 & 15;
        const int row0 = (s >> 1) * 64 + qr;
        const int cl0 = (s & 1) * 64 + qc;
        const int colw = G * 1024 + xcd * 128 + cl0;
        f32x4 acc[2][2]; ZACC(acc);
        gtile(acc, p.xg + row0 * 1024, 1024,
              p.wih + (size_t)colw * 1024, 1024, 1024, r16, kq);
#pragma unroll
        for (int ii = 0; ii < 2; ++ii)
#pragma unroll
          for (int jj = 0; jj < 2; ++jj)
#pragma unroll
            for (int qq = 0; qq < 4; ++qq) {
              const int row = row0 + ii * 16 + kq * 4 + qq;
              const int jc = jj * 16 + r16;
              p.giX[((size_t)xcd * 512 + row) * 384 + G * 128 + cl0 + jc] =
                  acc[ii][jj][qq] + p.bih[colw + jc];
            }
        setflag(FLp(1, t));
      }
      if (slot < 32) {
        waitflag(FGp(0, t), 128);
        const int i0 = 16 + slot;
        const int G = i0 >> 4, s = i0 & 15;
        const int row0 = (s >> 1) * 64 + qr;
        const int cl0 = (s & 1) * 64 + qc;
        const int colw = G * 1024 + xcd * 128 + cl0;
        f32x4 acc[2][2]; ZACC(acc);
        gtile(acc, p.xg + row0 * 1024, 1024,
              p.wih + (size_t)colw * 1024, 1024, 1024, r16, kq);
#pragma unroll
        for (int ii = 0; ii < 2; ++ii)
#pragma unroll
          for (int jj = 0; jj < 2; ++jj)
#pragma unroll
            for (int qq = 0; qq < 4; ++qq) {
              const int row = row0 + ii * 16 + kq * 4 + qq;
              const int jc = jj * 16 + r16;
              p.giX[((size_t)xcd * 512 + row) * 384 + G * 128 + cl0 + jc] =
                  acc[ii][jj][qq] + p.bih[colw + jc];
            }
        setflag(FLp(1, t));
      }
    }

    // ---- Ph2c: bpri(t-1) [slots 32..47] ----
    if (slot >= 32 && slot < 48 && t >= 1) {
      waitflag(FGp(1, t), 128);
      waitflag(FGp(3, t - 1), 64);
      const int s = slot - 32;
      const int row0 = (s >> 1) * 64 + qr;
      const int cl0 = (s & 1) * 64 + qc;
      const int colw = xcd * 128 + cl0;
      f32x4 acc[2][2]; ZACC(acc);
      gtile(acc, bprev + row0 * 1024, 1024,
            p.wbpri + (size_t)colw * 1024, 1024, 1024, r16, kq);
#pragma unroll
      for (int ii = 0; ii < 2; ++ii)
#pragma unroll
        for (int jj = 0; jj < 2; ++jj)
#pragma unroll
          for (int qq = 0; qq < 4; ++qq) {
            const int row = row0 + ii * 16 + kq * 4 + qq;
            const int col = colw + jj * 16 + r16;
            p.hprig[row * 1024 + col] = f2bf(fmaxf(acc[ii][jj][qq] + p.bbpri[col], 0.f));
          }
      setflag(FGp(2, t));
    }

    // ---- Ph2d: spri(t-1) [slots 48..55] ----
    if (slot >= 48 && slot < 56 && t >= 1) {
      waitflag(FGp(2, t), 128);
      const int s = slot - 48;
      const int gem = wid & 1, rh = wid >> 1;
      f32x4 acc[2][2]; ZACC(acc);
      gtile(acc, p.hprig + (size_t)(s * 64 + rh * 32) * 1024, 1024,
            p.wspri + (size_t)((gem ? 256 : 0) + xcd * 32) * 1024, 1024, 1024, r16, kq);
#pragma unroll
      for (int ii = 0; ii < 2; ++ii)
#pragma unroll
        for (int jj = 0; jj < 2; ++jj)
#pragma unroll
          for (int qq = 0; qq < 4; ++qq)
            sp_lds[gem][rh * 32 + ii * 16 + kq * 4 + qq][jj * 16 + r16] = acc[ii][jj][qq];
      __syncthreads();
      const int rr = threadIdx.x >> 2;
      const int cb = (threadIdx.x & 3) * 8;
      const int tt = t - 1;
      const int row = s * 64 + rr;
#pragma unroll
      for (int e = 0; e < 8; ++e) {
        const int cl = cb + e;
        const int c = xcd * 32 + cl;
        const float mu = sp_lds[0][rr][cl] + p.bspri[c];
        const float hp = sp_lds[1][rr][cl] + p.bspri[256 + c];
        const float sd = softplus_(hp) + 0.1f;
        const size_t idx = (size_t)tt * (NB * NS) + (size_t)row * NS + c;
        p.out[OUT_SPRI + idx] = mu + sd * p.npri[idx];
        p.out[OUT_MUPRI + idx] = mu;
        p.out[OUT_STDPRI + idx] = sd;
      }
      setflag(FGp(3, t));
    }

    // ---- Ph3: GRU epilogue [slots 0..15] ----
    if (slot < 16 && t < NT) {
      waitflag(FLp(1, t), 48);
      waitflag(FLp(2, t), 48);
      if (t >= 2) waitflag(FGp(2, t - 1), 128);  // bpri(t-2) done reading bn[t&1]
      const int rl = threadIdx.x >> 3;
      const int row = slot * 32 + rl;
      const int cl0 = (threadIdx.x & 7) * 16;
      const float* gi = p.giX + ((size_t)xcd * 512 + row) * 384;
      const u16* gh = p.ghX + ((size_t)xcd * 512 + row) * 384;
      float* hr = p.hfX + ((size_t)xcd * 512 + row) * 128;
      float* orow = p.out + OUT_B + (size_t)t * (NB * NBEL) + (size_t)row * NBEL;
#pragma unroll 4
      for (int e = 0; e < 16; ++e) {
        const int cl = cl0 + e;
        const int c = xcd * 128 + cl;
        const float r = sigm(gi[cl] + bf2f(gh[cl]));
        const float z = sigm(gi[128 + cl] + bf2f(gh[128 + cl]));
        const float n = tanhf(gi[256 + cl] + r * bf2f(gh[256 + cl]));
        const float h = hr[cl];
        const float bnew = (1.f - z) * n + z * h;
        hr[cl] = bnew;
        bcur[row * 1024 + c] = f2bf(bnew);
        orow[c] = bnew;
      }
      setflag(FGp(1, t + 1));
    }

    // ---- Ph4: hbB(t) [slots 16..31] ----
    if (slot >= 16 && slot < 32 && t < NT) {
      waitflag(FGp(1, t + 1), 128);
      waitflag(FLp(0, t), 16);
      const int s = slot - 16;
      const int row0 = (s >> 1) * 64 + qr;
      const int cl0 = (s & 1) * 64 + qc;
      const int colw = xcd * 128 + cl0;
      f32x4 acc[2][2]; ZACC(acc);
      gtile(acc, bcur + row0 * 1024, 1024,
            p.wbpos + (size_t)colw * 2048, 2048, 1024, r16, kq);
      const u16* ho = p.hbo + ((size_t)xcd * 2 + (t & 1)) * 65536;
#pragma unroll
      for (int ii = 0; ii < 2; ++ii)
#pragma unroll
        for (int jj = 0; jj < 2; ++jj)
#pragma unroll
          for (int qq = 0; qq < 4; ++qq) {
            const int row = row0 + ii * 16 + kq * 4 + qq;
            const int cl = cl0 + jj * 16 + r16;
            const float v = acc[ii][jj][qq] + bf2f(ho[row * 128 + cl]) + p.bbpos[xcd * 128 + cl];
            p.hbg[row * 1024 + xcd * 128 + cl] = f2bf(fmaxf(v, 0.f));
          }
      setflag(FGp(4, t));
    }

    // ---- Ph5: spos(t) [slots 56..63] ----
    if (slot >= 56 && t < NT) {
      waitflag(FGp(4, t), 128);
      const int s = slot - 56;
      const int gem = wid & 1, rh = wid >> 1;
      f32x4 acc[2][2]; ZACC(acc);
      gtile(acc, p.hbg + (size_t)(s * 64 + rh * 32) * 1024, 1024,
            p.wspos + (size_t)((gem ? 256 : 0) + xcd * 32) * 1024, 1024, 1024, r16, kq);
#pragma unroll
      for (int ii = 0; ii < 2; ++ii)
#pragma unroll
        for (int jj = 0; jj < 2; ++jj)
#pragma unroll
          for (int qq = 0; qq < 4; ++qq)
            sp_lds[gem][rh * 32 + ii * 16 + kq * 4 + qq][jj * 16 + r16] = acc[ii][jj][qq];
      __syncthreads();
      const int rr = threadIdx.x >> 2;
      const int cb = (threadIdx.x & 3) * 8;
      const int row = s * 64 + rr;
#pragma unroll
      for (int e = 0; e < 8; ++e) {
        const int cl = cb + e;
        const int c = xcd * 32 + cl;
        const float mu = sp_lds[0][rr][cl] + p.bspos[c];
        const float hq = sp_lds[1][rr][cl] + p.bspos[256 + c];
        const float sd = softplus_(hq) + 0.1f;
        const size_t idx = (size_t)t * (NB * NS) + (size_t)row * NS + c;
        const float sq = mu + sd * p.npos[idx];
        p.out[OUT_SPOS + idx] = sq;
        p.out[OUT_MUPOS + idx] = mu;
        p.out[OUT_STDPOS + idx] = sd;
        const float mn = (t < NT - 1) ? p.Mp[(t + 1) * NB + row] : 1.f;
        p.smaskg[row * 256 + c] = f2bf(sq * mn);
      }
      setflag(FGp(5, t + 1));
    }
  }
#undef FGp
#undef FLp
}

// ======================= fallback: proven R5 path =======================
__device__ __forceinline__ void red_write(float* L, f32x4 (&acc)[2][2], int l) {
  const int base = l * 16;
#pragma unroll
  for (int i = 0; i < 2; ++i)
#pragma unroll
    for (int j = 0; j < 2; ++j)
#pragma unroll
      for (int q = 0; q < 4; ++q)
        L[base + (i * 2 + j) * 4 + q] = acc[i][j][q];
}
__device__ __forceinline__ void red_add(const float* L, f32x4 (&acc)[2][2], int l) {
  const int base = l * 16;
#pragma unroll
  for (int i = 0; i < 2; ++i)
#pragma unroll
    for (int j = 0; j < 2; ++j)
#pragma unroll
      for (int q = 0; q < 4; ++q)
        acc[i][j][q] += L[base + (i * 2 + j) * 4 + q];
}

__global__ __launch_bounds__(256) void init_carry_k(
    const float* __restrict__ s0, const float* __restrict__ b0,
    const float* __restrict__ Mptr, u16* __restrict__ smask,
    u16* __restrict__ bbf0, float* __restrict__ hf) {
  for (int i = blockIdx.x * blockDim.x + threadIdx.x; i < NB * NBEL;
       i += gridDim.x * blockDim.x) {
    float b = b0[i];
    bbf0[i] = f2bf(b);
    hf[i] = b;
    if (i < NB * NS) {
      int row = i >> 8;
      smask[i] = f2bf(s0[i] * Mptr[row]);
    }
  }
}

__global__ __launch_bounds__(512, 2) void kA(
    const u16* __restrict__ smask, const float* __restrict__ Af,
    const u16* __restrict__ wsa, const float* __restrict__ bsa,
    u16* __restrict__ xbf, const float* __restrict__ Of,
    const u16* __restrict__ wbpos, float* __restrict__ hbO, int t) {
  __shared__ float lred[4][1024];
  const int l = threadIdx.x & 63, r16 = l & 15, kq = l >> 4;
  const int wid8 = threadIdx.x >> 6;
  const int wid = wid8 & 3, kh = wid8 >> 2;
  if (blockIdx.x < 128) {
    const int g = blockIdx.x, bm = g >> 4, bn = g & 15;
    const int row0 = bm * 64 + (wid >> 1) * 32;
    const int col0 = bn * 64 + (wid & 1) * 32;
    f32x4 acc[2][2]; ZACC(acc);
    const u16* A0 = smask + (row0 + r16) * NS + kq * 8;
    const u16* A1 = A0 + 16 * NS;
    const u16* B0 = wsa + (size_t)(col0 + r16) * 320 + kq * 8;
    const u16* B1 = B0 + 16 * 320;
    if (kh == 0) {
#pragma unroll
      for (int k = 0; k < 160; k += 32) {
        bf16x8 a0 = ld8bf(A0 + k), a1 = ld8bf(A1 + k);
        bf16x8 b0 = ld8bf(B0 + k), b1 = ld8bf(B1 + k);
        Q4(acc, a0, a1, b0, b1);
      }
    } else {
#pragma unroll
      for (int k = 160; k < 256; k += 32) {
        bf16x8 a0 = ld8bf(A0 + k), a1 = ld8bf(A1 + k);
        bf16x8 b0 = ld8bf(B0 + k), b1 = ld8bf(B1 + k);
        Q4(acc, a0, a1, b0, b1);
      }
      const float* F0 = Af + (size_t)t * (NB * NA) + (row0 + r16) * NA + kq * 8;
      const float* F1 = F0 + 16 * NA;
      const u16* C0 = wsa + (size_t)(col0 + r16) * 320 + 256 + kq * 8;
      const u16* C1 = C0 + 16 * 320;
#pragma unroll
      for (int k = 0; k < 64; k += 32) {
        bf16x8 a0 = cvt8(F0 + k), a1 = cvt8(F1 + k);
        bf16x8 b0 = ld8bf(C0 + k), b1 = ld8bf(C1 + k);
        Q4(acc, a0, a1, b0, b1);
      }
      red_write(lred[wid], acc, l);
    }
    __syncthreads();
    if (kh == 0) {
      red_add(lred[wid], acc, l);
#pragma unroll
      for (int i = 0; i < 2; ++i)
#pragma unroll
        for (int j = 0; j < 2; ++j)
#pragma unroll
          for (int q = 0; q < 4; ++q) {
            const int row = row0 + i * 16 + kq * 4 + q;
            const int col = col0 + j * 16 + r16;
            xbf[row * NBEL + col] = f2bf(fmaxf(acc[i][j][q] + bsa[col], 0.f));
          }
    }
  } else {
    const int g = blockIdx.x - 128, bm = g >> 4, bn = g & 15;
    const int row0 = bm * 64 + (wid >> 1) * 32;
    const int col0 = bn * 64 + (wid & 1) * 32;
    f32x4 acc[2][2]; ZACC(acc);
    const float* F0 = Of + (size_t)t * (NB * NBEL) + (row0 + r16) * NBEL + kh * 512 + kq * 8;
    const float* F1 = F0 + 16 * NBEL;
    const u16* B0 = wbpos + (size_t)(col0 + r16) * 2048 + 1024 + kh * 512 + kq * 8;
    const u16* B1 = B0 + 16 * 2048;
#pragma unroll 4
    for (int k = 0; k < 512; k += 32) {
      bf16x8 a0 = cvt8(F0 + k), a1 = cvt8(F1 + k);
      bf16x8 b0 = ld8bf(B0 + k), b1 = ld8bf(B1 + k);
      Q4(acc, a0, a1, b0, b1);
    }
    if (kh == 1) red_write(lred[wid], acc, l);
    __syncthreads();
    if (kh == 0) {
      red_add(lred[wid], acc, l);
#pragma unroll
      for (int i = 0; i < 2; ++i)
#pragma unroll
        for (int j = 0; j < 2; ++j)
#pragma unroll
          for (int q = 0; q < 4; ++q) {
            const int row = row0 + i * 16 + kq * 4 + q;
            const int col = col0 + j * 16 + r16;
            hbO[row * NBEL + col] = acc[i][j][q];
          }
    }
  }
}

__global__ __launch_bounds__(512, 2) void kB(
    const u16* __restrict__ xbf, const u16* __restrict__ bprev,
    const u16* __restrict__ wih, const u16* __restrict__ whh,
    const float* __restrict__ bih, const float* __restrict__ bhh,
    float* __restrict__ hf, u16* __restrict__ bcur, float* __restrict__ out,
    const u16* __restrict__ wbpri, const float* __restrict__ bbpri,
    u16* __restrict__ hpri, int t) {
  __shared__ float lred[4][3][1024];
  const int l = threadIdx.x & 63, r16 = l & 15, kq = l >> 4;
  const int wid8 = threadIdx.x >> 6;
  const int wid = wid8 & 3, kh = wid8 >> 2;
  if (blockIdx.x < 128) {
    if (t >= NT) return;
    const int g = blockIdx.x, bm = g >> 4, bn = g & 15;
    const int row0 = bm * 64 + (wid >> 1) * 32;
    const int col0 = bn * 64 + (wid & 1) * 32;
    f32x4 ar[2][2], az[2][2], an[2][2];
    ZACC(ar); ZACC(az); ZACC(an);
    const u16* Asrc = (kh == 0) ? xbf : bprev;
    const u16* W = (kh == 0) ? wih : whh;
    const u16* A0 = Asrc + (row0 + r16) * NBEL + kq * 8;
    const u16* A1 = A0 + 16 * NBEL;
    const u16* Br0 = W + (size_t)(col0 + r16) * NBEL + kq * 8;
    const u16* Br1 = Br0 + 16 * NBEL;
    const u16* Bz0 = W + (size_t)(col0 + 1024 + r16) * NBEL + kq * 8;
    const u16* Bz1 = Bz0 + 16 * NBEL;
    const u16* Bn0 = W + (size_t)(col0 + 2048 + r16) * NBEL + kq * 8;
    const u16* Bn1 = Bn0 + 16 * NBEL;
#pragma unroll 4
    for (int k = 0; k < NBEL; k += 32) {
      bf16x8 a0 = ld8bf(A0 + k), a1 = ld8bf(A1 + k);
      bf16x8 b0 = ld8bf(Br0 + k), b1 = ld8bf(Br1 + k);
      Q4(ar, a0, a1, b0, b1);
      bf16x8 c0 = ld8bf(Bz0 + k), c1 = ld8bf(Bz1 + k);
      Q4(az, a0, a1, c0, c1);
      bf16x8 d0 = ld8bf(Bn0 + k), d1 = ld8bf(Bn1 + k);
      Q4(an, a0, a1, d0, d1);
    }
    if (kh == 1) {
      red_write(&lred[wid][0][0], ar, l);
      red_write(&lred[wid][1][0], az, l);
      red_write(&lred[wid][2][0], an, l);
    }
    __syncthreads();
    if (kh == 0) {
      const int base = l * 16;
#pragma unroll
      for (int i = 0; i < 2; ++i)
#pragma unroll
        for (int j = 0; j < 2; ++j)
#pragma unroll
          for (int q = 0; q < 4; ++q) {
            const int row = row0 + i * 16 + kq * 4 + q;
            const int c = col0 + j * 16 + r16;
            const int li = base + (i * 2 + j) * 4 + q;
            const float r = sigm(ar[i][j][q] + bih[c] + lred[wid][0][li] + bhh[c]);
            const float z = sigm(az[i][j][q] + bih[c + 1024] + lred[wid][1][li] + bhh[c + 1024]);
            const float n = tanhf(an[i][j][q] + bih[c + 2048] +
                                  r * (lred[wid][2][li] + bhh[c + 2048]));
            const float h = hf[row * NBEL + c];
            const float bnew = (1.f - z) * n + z * h;
            hf[row * NBEL + c] = bnew;
            bcur[row * NBEL + c] = f2bf(bnew);
            out[OUT_B + (size_t)t * (NB * NBEL) + row * NBEL + c] = bnew;
          }
    }
  } else {
    if (t < 1) return;
    const int g = blockIdx.x - 128, bm = g >> 4, bn = g & 15;
    const int row0 = bm * 64 + (wid >> 1) * 32;
    const int col0 = bn * 64 + (wid & 1) * 32;
    f32x4 acc[2][2]; ZACC(acc);
    const u16* A0 = bprev + (row0 + r16) * NBEL + kh * 512 + kq * 8;
    const u16* A1 = A0 + 16 * NBEL;
    const u16* B0 = wbpri + (size_t)(col0 + r16) * NBEL + kh * 512 + kq * 8;
    const u16* B1 = B0 + 16 * NBEL;
#pragma unroll 4
    for (int k = 0; k < 512; k += 32) {
      bf16x8 a0 = ld8bf(A0 + k), a1 = ld8bf(A1 + k);
      bf16x8 b0 = ld8bf(B0 + k), b1 = ld8bf(B1 + k);
      Q4(acc, a0, a1, b0, b1);
    }
    if (kh == 1) red_write(&lred[wid][0][0], acc, l);
    __syncthreads();
    if (kh == 0) {
      red_add(&lred[wid][0][0], acc, l);
#pragma unroll
      for (int i = 0; i < 2; ++i)
#pragma unroll
        for (int j = 0; j < 2; ++j)
#pragma unroll
          for (int q = 0; q < 4; ++q) {
            const int row = row0 + i * 16 + kq * 4 + q;
            const int col = col0 + j * 16 + r16;
            hpri[row * NBEL + col] = f2bf(fmaxf(acc[i][j][q] + bbpri[col], 0.f));
          }
    }
  }
}

__global__ __launch_bounds__(512, 2) void kC(
    const u16* __restrict__ bcur, const u16* __restrict__ wbpos,
    const float* __restrict__ bbpos, const float* __restrict__ hbO,
    u16* __restrict__ hbbf,
    const u16* __restrict__ hpri, const u16* __restrict__ wspri,
    const float* __restrict__ bspri, const float* __restrict__ npri,
    float* __restrict__ out, int t) {
  __shared__ float lred[4][2][1024];
  const int l = threadIdx.x & 63, r16 = l & 15, kq = l >> 4;
  const int wid8 = threadIdx.x >> 6;
  const int wid = wid8 & 3, kh = wid8 >> 2;
  if (blockIdx.x < 128) {
    if (t >= NT) return;
    const int g = blockIdx.x, bm = g >> 4, bn = g & 15;
    const int row0 = bm * 64 + (wid >> 1) * 32;
    const int col0 = bn * 64 + (wid & 1) * 32;
    f32x4 acc[2][2]; ZACC(acc);
    const u16* A0 = bcur + (row0 + r16) * NBEL + kh * 512 + kq * 8;
    const u16* A1 = A0 + 16 * NBEL;
    const u16* B0 = wbpos + (size_t)(col0 + r16) * 2048 + kh * 512 + kq * 8;
    const u16* B1 = B0 + 16 * 2048;
#pragma unroll 4
    for (int k = 0; k < 512; k += 32) {
      bf16x8 a0 = ld8bf(A0 + k), a1 = ld8bf(A1 + k);
      bf16x8 b0 = ld8bf(B0 + k), b1 = ld8bf(B1 + k);
      Q4(acc, a0, a1, b0, b1);
    }
    if (kh == 1) red_write(&lred[wid][0][0], acc, l);
    __syncthreads();
    if (kh == 0) {
      red_add(&lred[wid][0][0], acc, l);
#pragma unroll
      for (int i = 0; i < 2; ++i)
#pragma unroll
        for (int j = 0; j < 2; ++j)
#pragma unroll
          for (int q = 0; q < 4; ++q) {
            const int row = row0 + i * 16 + kq * 4 + q;
            const int col = col0 + j * 16 + r16;
            const float v = acc[i][j][q] + hbO[row * NBEL + col] + bbpos[col];
            hbbf[row * NBEL + col] = f2bf(fmaxf(v, 0.f));
          }
    }
  } else {
    if (t < 1) return;
    const int g = blockIdx.x - 128, bm = g >> 2, bn = g & 3;
    const int row0 = bm * 64 + (wid >> 1) * 32;
    const int c0 = bn * 64 + (wid & 1) * 32;
    f32x4 am[2][2], ah[2][2];
    ZACC(am); ZACC(ah);
    const u16* A0 = hpri + (row0 + r16) * NBEL + kh * 512 + kq * 8;
    const u16* A1 = A0 + 16 * NBEL;
    const u16* Bm0 = wspri + (size_t)(c0 + r16) * NBEL + kh * 512 + kq * 8;
    const u16* Bm1 = Bm0 + 16 * NBEL;
    const u16* Bh0 = wspri + (size_t)(c0 + 256 + r16) * NBEL + kh * 512 + kq * 8;
    const u16* Bh1 = Bh0 + 16 * NBEL;
#pragma unroll 4
    for (int k = 0; k < 512; k += 32) {
      bf16x8 a0 = ld8bf(A0 + k), a1 = ld8bf(A1 + k);
      bf16x8 m0 = ld8bf(Bm0 + k), m1 = ld8bf(Bm1 + k);
      Q4(am, a0, a1, m0, m1);
      bf16x8 h0 = ld8bf(Bh0 + k), h1 = ld8bf(Bh1 + k);
      Q4(ah, a0, a1, h0, h1);
    }
    if (kh == 1) {
      red_write(&lred[wid][0][0], am, l);
      red_write(&lred[wid][1][0], ah, l);
    }
    __syncthreads();
    if (kh == 0) {
      red_add(&lred[wid][0][0], am, l);
      red_add(&lred[wid][1][0], ah, l);
      const int tt = t - 1;
#pragma unroll
      for (int i = 0; i < 2; ++i)
#pragma unroll
        for (int j = 0; j < 2; ++j)
#pragma unroll
          for (int q = 0; q < 4; ++q) {
            const int row = row0 + i * 16 + kq * 4 + q;
            const int c = c0 + j * 16 + r16;
            const size_t idx = (size_t)tt * (NB * NS) + row * NS + c;
            const float mu = am[i][j][q] + bspri[c];
            const float hp = ah[i][j][q] + bspri[c + 256];
            const float sd = softplus_(hp) + 0.1f;
            out[OUT_SPRI + idx] = mu + sd * npri[idx];
            out[OUT_MUPRI + idx] = mu;
            out[OUT_STDPRI + idx] = sd;
          }
    }
  }
}

__global__ __launch_bounds__(512, 2) void kD(
    const u16* __restrict__ hbbf, const u16* __restrict__ wspos,
    const float* __restrict__ bspos, const float* __restrict__ npos,
    const float* __restrict__ Mptr, float* __restrict__ out,
    u16* __restrict__ smask, int t) {
  __shared__ float lred[4][2][1024];
  const int l = threadIdx.x & 63, r16 = l & 15, kq = l >> 4;
  const int wid8 = threadIdx.x >> 6;
  const int wid = wid8 & 3, kh = wid8 >> 2;
  const int g = blockIdx.x, bm = g >> 2, bn = g & 3;
  const int row0 = bm * 64 + (wid >> 1) * 32;
  const int c0 = bn * 64 + (wid & 1) * 32;
  f32x4 am[2][2], ah[2][2];
  ZACC(am); ZACC(ah);
  const u16* A0 = hbbf + (row0 + r16) * NBEL + kh * 512 + kq * 8;
  const u16* A1 = A0 + 16 * NBEL;
  const u16* Bm0 = wspos + (size_t)(c0 + r16) * NBEL + kh * 512 + kq * 8;
  const u16* Bm1 = Bm0 + 16 * NBEL;
  const u16* Bh0 = wspos + (size_t)(c0 + 256 + r16) * NBEL + kh * 512 + kq * 8;
  const u16* Bh1 = Bh0 + 16 * NBEL;
#pragma unroll 4
  for (int k = 0; k < 512; k += 32) {
    bf16x8 a0 = ld8bf(A0 + k), a1 = ld8bf(A1 + k);
    bf16x8 m0 = ld8bf(Bm0 + k), m1 = ld8bf(Bm1 + k);
    Q4(am, a0, a1, m0, m1);
    bf16x8 h0 = ld8bf(Bh0 + k), h1 = ld8bf(Bh1 + k);
    Q4(ah, a0, a1, h0, h1);
  }
  if (kh == 1) {
    red_write(&lred[wid][0][0], am, l);
    red_write(&lred[wid][1][0], ah, l);
  }
  __syncthreads();
  if (kh == 0) {
    red_add(&lred[wid][0][0], am, l);
    red_add(&lred[wid][1][0], ah, l);
#pragma unroll
    for (int i = 0; i < 2; ++i)
#pragma unroll
      for (int j = 0; j < 2; ++j)
#pragma unroll
        for (int q = 0; q < 4; ++q) {
          const int row = row0 + i * 16 + kq * 4 + q;
          const int c = c0 + j * 16 + r16;
          const float mu = am[i][j][q] + bspos[c];
          const float hq = ah[i][j][q] + bspos[c + 256];
          const float sd = softplus_(hq) + 0.1f;
          const size_t idx = (size_t)t * (NB * NS) + row * NS + c;
          const float sq = mu + sd * npos[idx];
          out[OUT_SPOS + idx] = sq;
          out[OUT_MUPOS + idx] = mu;
          out[OUT_STDPOS + idx] = sd;
          const float mn = (t < NT - 1) ? Mptr[(t + 1) * NB + row] : 1.f;
          smask[row * NS + c] = f2bf(sq * mn);
        }
  }
}

extern "C" void kernel_launch(void* const* d_in, const int* in_sizes, int n_in,
                              void* d_out, int out_size, void* d_ws, size_t ws_size,
                              hipStream_t stream) {
  const float* s0 = (const float*)d_in[0];
  const float* Af = (const float*)d_in[1];
  const float* b0 = (const float*)d_in[2];
  const float* Of = (const float*)d_in[3];
  const float* Mp = (const float*)d_in[4];
  const float* npri = (const float*)d_in[5];
  const float* npos = (const float*)d_in[6];
  const float* Wsa = (const float*)d_in[7];
  const float* bsa = (const float*)d_in[8];
  const float* Wih = (const float*)d_in[9];
  const float* bih = (const float*)d_in[10];
  const float* Whh = (const float*)d_in[11];
  const float* bhh = (const float*)d_in[12];
  const float* Wbpri = (const float*)d_in[13];
  const float* bbpri = (const float*)d_in[14];
  const float* Wspri = (const float*)d_in[15];
  const float* bspri = (const float*)d_in[16];
  const float* Wbpos = (const float*)d_in[17];
  const float* bbpos = (const float*)d_in[18];
  const float* Wspos = (const float*)d_in[19];
  const float* bspos = (const float*)d_in[20];

  float* out = (float*)d_out;
  char* ws = (char*)d_ws;
  u16* wbase   = (u16*)ws;
  u16* wsa_b   = wbase;
  u16* wih_b   = wbase + 327680;
  u16* whh_b   = wbase + 3473408;
  u16* wbpri_b = wbase + 6619136;
  u16* wspri_b = wbase + 7667712;
  u16* wbpos_b = wbase + 8192000;
  u16* wspos_b = wbase + 10289152;
  // weights end at byte 21,626,880

  // column-partitioned scan layout
  unsigned* flagsG = (unsigned*)(ws + 21626880);       // 6*68 u32
  unsigned* flagsL = (unsigned*)(ws + 21626880 + 1632); // 8*3*68 u32
  u16*   smaskg = (u16*)  (ws + 21643264);  // [512][256]
  u16*   xg     = (u16*)  (ws + 21905408);  // [512][1024]
  u16*   bn0    = (u16*)  (ws + 22953984);  // [512][1024]
  u16*   bn1    = (u16*)  (ws + 24002560);  // [512][1024]
  u16*   hbg    = (u16*)  (ws + 25051136);  // [512][1024]
  u16*   hprig  = (u16*)  (ws + 26099712);  // [512][1024]
  u16*   hbo    = (u16*)  (ws + 27148288);  // [8][2][512][128]
  float* giX    = (float*)(ws + 29245440);  // [8][512][384] f32
  u16*   ghX    = (u16*)  (ws + 35536896);  // [8][512][384] bf16
  float* hfX    = (float*)(ws + 38682624);  // [8][512][128] f32
  // end 40,779,776 bytes

  cvt_weights_k<<<2048, 256, 0, stream>>>(Wsa, Wih, Whh, Wbpri, Wspri, Wbpos,
                                          Wspos, wbase);
  init2_k<<<2048, 256, 0, stream>>>(s0, b0, Mp, smaskg, bn1, hfX, flagsG);

  SP2 p;
  p.Af = Af; p.Of = Of; p.Mp = Mp; p.npri = npri; p.npos = npos;
  p.bsa = bsa; p.bih = bih; p.bhh = bhh; p.bbpri = bbpri; p.bspri = bspri;
  p.bbpos = bbpos; p.bspos = bspos;
  p.wsa = wsa_b; p.wih = wih_b; p.whh = whh_b; p.wbpri = wbpri_b;
  p.wspri = wspri_b; p.wbpos = wbpos_b; p.wspos = wspos_b;
  p.out = out;
  p.smaskg = smaskg; p.xg = xg; p.bn0 = bn0; p.bn1 = bn1;
  p.hbg = hbg; p.hprig = hprig; p.hbo = hbo; p.ghX = ghX;
  p.giX = giX; p.hfX = hfX;
  p.flagsG = flagsG; p.flagsL = flagsL;

  void* args[] = {(void*)&p};
  hipError_t err = hipLaunchCooperativeKernel(
      reinterpret_cast<const void*>(&rssm_scan2), dim3(512), dim3(256),
      args, 0, stream);
  if (err == hipSuccess) return;

  // -------- fallback: proven R5 multi-kernel path --------
  u16*   smask = (u16*)  (ws + 21626880);
  u16*   bbf0  = (u16*)  (ws + 21889024);
  u16*   bbf1  = (u16*)  (ws + 22937600);
  float* hf    = (float*)(ws + 23986176);
  u16*   xbf   = (u16*)  (ws + 26083328);
  float* hbO   = (float*)(ws + 27131904);
  u16*   hbbf  = (u16*)  (ws + 29229056);
  u16*   hpri  = (u16*)  (ws + 30277632);

  init_carry_k<<<2048, 256, 0, stream>>>(s0, b0, Mp, smask, bbf0, hf);
  for (int t = 0; t < NT; ++t) {
    const u16* bprev = (t & 1) ? bbf1 : bbf0;
    u16* bcur = (t & 1) ? bbf0 : bbf1;
    kA<<<256, 512, 0, stream>>>(smask, Af, wsa_b, bsa, xbf, Of, wbpos_b, hbO, t);
    kB<<<256, 512, 0, stream>>>(xbf, bprev, wih_b, whh_b, bih, bhh, hf, bcur,
                                out, wbpri_b, bbpri, hpri, t);
    kC<<<160, 512, 0, stream>>>(bcur, wbpos_b, bbpos, hbO, hbbf,
                                hpri, wspri_b, bspri, npri, out, t);
    kD<<<32, 512, 0, stream>>>(hbbf, wspos_b, bspos, npos, Mp, out, smask, t);
  }
  {
    const int t = NT;
    const u16* bprev = (t & 1) ? bbf1 : bbf0;
    u16* bcur = (t & 1) ? bbf0 : bbf1;
    kB<<<256, 512, 0, stream>>>(xbf, bprev, wih_b, whh_b, bih, bhh, hf, bcur,
                                out, wbpri_b, bbpri, hpri, t);
    kC<<<160, 512, 0, stream>>>(bcur, wbpos_b, bbpos, hbO, hbbf,
                                hpri, wspri_b, bspri, npri, out, t);
  }
}

// Round 9
// 13540.175 us; speedup vs baseline: 1.2066x; 1.0680x over previous
//
#include <hip/hip_runtime.h>
#include <hip/hip_bf16.h>
#include <math.h>

typedef short bf16x8 __attribute__((ext_vector_type(8)));
typedef float f32x4 __attribute__((ext_vector_type(4)));
typedef unsigned short u16;

#define NT 64
#define NB 512
#define NS 256
#define NA 64
#define NBEL 1024

// d_out element offsets (f32 elements)
#define OUT_B      0
#define OUT_SPRI   33554432
#define OUT_MUPRI  41943040
#define OUT_STDPRI 50331648
#define OUT_SPOS   58720256
#define OUT_MUPOS  67108864
#define OUT_STDPOS 75497472

__device__ __forceinline__ f32x4 mfma16(bf16x8 a, bf16x8 b, f32x4 c) {
  return __builtin_amdgcn_mfma_f32_16x16x32_bf16(a, b, c, 0, 0, 0);
}

__device__ __forceinline__ u16 f2bf(float f) {
  union { float f; unsigned u; } v; v.f = f;
  return (u16)((v.u + 0x7FFFu + ((v.u >> 16) & 1u)) >> 16);
}

__device__ __forceinline__ bf16x8 ld8bf(const u16* p) { return *(const bf16x8*)p; }

__device__ __forceinline__ bf16x8 cvt8(const float* p) {
  const float4 lo = *(const float4*)p;
  const float4 hi = *(const float4*)(p + 4);
  bf16x8 v;
  v[0] = (short)f2bf(lo.x); v[1] = (short)f2bf(lo.y);
  v[2] = (short)f2bf(lo.z); v[3] = (short)f2bf(lo.w);
  v[4] = (short)f2bf(hi.x); v[5] = (short)f2bf(hi.y);
  v[6] = (short)f2bf(hi.z); v[7] = (short)f2bf(hi.w);
  return v;
}

__device__ __forceinline__ float sigm(float x) { return 1.f / (1.f + __expf(-x)); }
__device__ __forceinline__ float softplus_(float x) {
  if (x > 20.f) return x;
  return log1pf(__expf(x));
}

#define ZACC(acc) { acc[0][0] = (f32x4){0.f,0.f,0.f,0.f}; acc[0][1] = (f32x4){0.f,0.f,0.f,0.f}; \
                    acc[1][0] = (f32x4){0.f,0.f,0.f,0.f}; acc[1][1] = (f32x4){0.f,0.f,0.f,0.f}; }

#define Q4(acc, a0v, a1v, b0v, b1v) \
  acc[0][0] = mfma16(a0v, b0v, acc[0][0]); \
  acc[0][1] = mfma16(a0v, b1v, acc[0][1]); \
  acc[1][0] = mfma16(a1v, b0v, acc[1][0]); \
  acc[1][1] = mfma16(a1v, b1v, acc[1][1]);

__device__ __forceinline__ void red_write(float* L, f32x4 (&acc)[2][2], int l) {
  const int base = l * 16;
#pragma unroll
  for (int i = 0; i < 2; ++i)
#pragma unroll
    for (int j = 0; j < 2; ++j)
#pragma unroll
      for (int q = 0; q < 4; ++q)
        L[base + (i * 2 + j) * 4 + q] = acc[i][j][q];
}
__device__ __forceinline__ void red_add(const float* L, f32x4 (&acc)[2][2], int l) {
  const int base = l * 16;
#pragma unroll
  for (int i = 0; i < 2; ++i)
#pragma unroll
    for (int j = 0; j < 2; ++j)
#pragma unroll
      for (int q = 0; q < 4; ++q)
        acc[i][j][q] += L[base + (i * 2 + j) * 4 + q];
}

// -------- P0: weights f32 -> bf16 --------
__global__ __launch_bounds__(256) void cvt_weights_k(
    const float* __restrict__ wsa, const float* __restrict__ wih,
    const float* __restrict__ whh, const float* __restrict__ wbpri,
    const float* __restrict__ wspri, const float* __restrict__ wbpos,
    const float* __restrict__ wspos, u16* __restrict__ dst) {
  const int S0 = 327680;
  const int S1 = S0 + 3145728;
  const int S2 = S1 + 3145728;
  const int S3 = S2 + 1048576;
  const int S4 = S3 + 524288;
  const int S5 = S4 + 2097152;
  const int S6 = S5 + 524288;
  for (int i = blockIdx.x * blockDim.x + threadIdx.x; i < S6;
       i += gridDim.x * blockDim.x) {
    float v;
    if (i < S0) v = wsa[i];
    else if (i < S1) v = wih[i - S0];
    else if (i < S2) v = whh[i - S1];
    else if (i < S3) v = wbpri[i - S2];
    else if (i < S4) v = wspri[i - S3];
    else if (i < S5) v = wbpos[i - S4];
    else v = wspos[i - S5];
    dst[i] = f2bf(v);
  }
}

// -------- P1: init carries --------
__global__ __launch_bounds__(256) void init_carry_k(
    const float* __restrict__ s0, const float* __restrict__ b0,
    const float* __restrict__ Mptr, u16* __restrict__ smask,
    u16* __restrict__ bbf0, float* __restrict__ hf) {
  for (int i = blockIdx.x * blockDim.x + threadIdx.x; i < NB * NBEL;
       i += gridDim.x * blockDim.x) {
    float b = b0[i];
    bbf0[i] = f2bf(b);
    hf[i] = b;
    if (i < NB * NS) {
      int row = i >> 8;
      smask[i] = f2bf(s0[i] * Mptr[row]);
    }
  }
}

// -------- spri device piece: 32 blocks (8 x 4), K-split 8-wave --------
__device__ __forceinline__ void dev_spri(
    int g, int wid, int kh, int r16, int kq, int l, int tt,
    const u16* __restrict__ hpri, const u16* __restrict__ wspri,
    const float* __restrict__ bspri, const float* __restrict__ npri,
    float* __restrict__ out, float* lred0, float* lred1) {
  const int bm = g >> 2, bn = g & 3;
  const int row0 = bm * 64 + (wid >> 1) * 32;
  const int c0 = bn * 64 + (wid & 1) * 32;
  f32x4 am[2][2], ah[2][2];
  ZACC(am); ZACC(ah);
  const u16* A0 = hpri + (row0 + r16) * NBEL + kh * 512 + kq * 8;
  const u16* A1 = A0 + 16 * NBEL;
  const u16* Bm0 = wspri + (size_t)(c0 + r16) * NBEL + kh * 512 + kq * 8;
  const u16* Bm1 = Bm0 + 16 * NBEL;
  const u16* Bh0 = wspri + (size_t)(c0 + 256 + r16) * NBEL + kh * 512 + kq * 8;
  const u16* Bh1 = Bh0 + 16 * NBEL;
#pragma unroll 4
  for (int k = 0; k < 512; k += 32) {
    bf16x8 a0 = ld8bf(A0 + k), a1 = ld8bf(A1 + k);
    bf16x8 m0 = ld8bf(Bm0 + k), m1 = ld8bf(Bm1 + k);
    Q4(am, a0, a1, m0, m1);
    bf16x8 h0 = ld8bf(Bh0 + k), h1 = ld8bf(Bh1 + k);
    Q4(ah, a0, a1, h0, h1);
  }
  if (kh == 1) {
    red_write(lred0, am, l);
    red_write(lred1, ah, l);
  }
  __syncthreads();
  if (kh == 0) {
    red_add(lred0, am, l);
    red_add(lred1, ah, l);
#pragma unroll
    for (int i = 0; i < 2; ++i)
#pragma unroll
      for (int j = 0; j < 2; ++j)
#pragma unroll
        for (int q = 0; q < 4; ++q) {
          const int row = row0 + i * 16 + kq * 4 + q;
          const int c = c0 + j * 16 + r16;
          const size_t idx = (size_t)tt * (NB * NS) + (size_t)row * NS + c;
          const float mu = am[i][j][q] + bspri[c];
          const float hp = ah[i][j][q] + bspri[c + 256];
          const float sd = softplus_(hp) + 0.1f;
          out[OUT_SPRI + idx] = mu + sd * npri[idx];
          out[OUT_MUPRI + idx] = mu;
          out[OUT_STDPRI + idx] = sd;
        }
  }
}

// ======================= kX0: x(0) [0..127] | hbO(0) [128..255] =======================
__global__ __launch_bounds__(512, 2) void kX0(
    const u16* __restrict__ smask, const float* __restrict__ Af,
    const u16* __restrict__ wsa, const float* __restrict__ bsa,
    u16* __restrict__ xg, const float* __restrict__ Of,
    const u16* __restrict__ wbpos, float* __restrict__ hbO0) {
  __shared__ float lred[4][1024];
  const int l = threadIdx.x & 63, r16 = l & 15, kq = l >> 4;
  const int wid8 = threadIdx.x >> 6;
  const int wid = wid8 & 3, kh = wid8 >> 2;
  if (blockIdx.x < 128) {
    const int g = blockIdx.x, bm = g >> 4, bn = g & 15;
    const int row0 = bm * 64 + (wid >> 1) * 32;
    const int col0 = bn * 64 + (wid & 1) * 32;
    f32x4 acc[2][2]; ZACC(acc);
    const u16* A0 = smask + (row0 + r16) * NS + kq * 8;
    const u16* A1 = A0 + 16 * NS;
    const u16* B0 = wsa + (size_t)(col0 + r16) * 320 + kq * 8;
    const u16* B1 = B0 + 16 * 320;
    if (kh == 0) {
#pragma unroll
      for (int k = 0; k < 160; k += 32) {
        bf16x8 a0 = ld8bf(A0 + k), a1 = ld8bf(A1 + k);
        bf16x8 b0 = ld8bf(B0 + k), b1 = ld8bf(B1 + k);
        Q4(acc, a0, a1, b0, b1);
      }
    } else {
#pragma unroll
      for (int k = 160; k < 256; k += 32) {
        bf16x8 a0 = ld8bf(A0 + k), a1 = ld8bf(A1 + k);
        bf16x8 b0 = ld8bf(B0 + k), b1 = ld8bf(B1 + k);
        Q4(acc, a0, a1, b0, b1);
      }
      const float* F0 = Af + (row0 + r16) * NA + kq * 8;
      const float* F1 = F0 + 16 * NA;
      const u16* C0 = wsa + (size_t)(col0 + r16) * 320 + 256 + kq * 8;
      const u16* C1 = C0 + 16 * 320;
#pragma unroll
      for (int k = 0; k < 64; k += 32) {
        bf16x8 a0 = cvt8(F0 + k), a1 = cvt8(F1 + k);
        bf16x8 b0 = ld8bf(C0 + k), b1 = ld8bf(C1 + k);
        Q4(acc, a0, a1, b0, b1);
      }
      red_write(lred[wid], acc, l);
    }
    __syncthreads();
    if (kh == 0) {
      red_add(lred[wid], acc, l);
#pragma unroll
      for (int i = 0; i < 2; ++i)
#pragma unroll
        for (int j = 0; j < 2; ++j)
#pragma unroll
          for (int q = 0; q < 4; ++q) {
            const int row = row0 + i * 16 + kq * 4 + q;
            const int col = col0 + j * 16 + r16;
            xg[row * NBEL + col] = f2bf(fmaxf(acc[i][j][q] + bsa[col], 0.f));
          }
    }
  } else {
    const int g = blockIdx.x - 128, bm = g >> 4, bn = g & 15;
    const int row0 = bm * 64 + (wid >> 1) * 32;
    const int col0 = bn * 64 + (wid & 1) * 32;
    f32x4 acc[2][2]; ZACC(acc);
    const float* F0 = Of + (row0 + r16) * NBEL + kh * 512 + kq * 8;
    const float* F1 = F0 + 16 * NBEL;
    const u16* B0 = wbpos + (size_t)(col0 + r16) * 2048 + 1024 + kh * 512 + kq * 8;
    const u16* B1 = B0 + 16 * 2048;
#pragma unroll 4
    for (int k = 0; k < 512; k += 32) {
      bf16x8 a0 = cvt8(F0 + k), a1 = cvt8(F1 + k);
      bf16x8 b0 = ld8bf(B0 + k), b1 = ld8bf(B1 + k);
      Q4(acc, a0, a1, b0, b1);
    }
    if (kh == 1) red_write(lred[wid], acc, l);
    __syncthreads();
    if (kh == 0) {
      red_add(lred[wid], acc, l);
#pragma unroll
      for (int i = 0; i < 2; ++i)
#pragma unroll
        for (int j = 0; j < 2; ++j)
#pragma unroll
          for (int q = 0; q < 4; ++q) {
            const int row = row0 + i * 16 + kq * 4 + q;
            const int col = col0 + j * 16 + r16;
            hbO0[row * NBEL + col] = acc[i][j][q];
          }
    }
  }
}

// ======================= kL1: gi+gh+GRU [0..127] | spri(t-1) [128..159] =======================
__global__ __launch_bounds__(512, 2) void kL1(
    const u16* __restrict__ xg, const u16* __restrict__ bprev,
    const u16* __restrict__ wih, const u16* __restrict__ whh,
    const float* __restrict__ bih, const float* __restrict__ bhh,
    float* __restrict__ hf, u16* __restrict__ bcur, float* __restrict__ out,
    const u16* __restrict__ hpri, const u16* __restrict__ wspri,
    const float* __restrict__ bspri, const float* __restrict__ npri, int t) {
  __shared__ float lred[4][3][1024];  // 48KB
  const int l = threadIdx.x & 63, r16 = l & 15, kq = l >> 4;
  const int wid8 = threadIdx.x >> 6;
  const int wid = wid8 & 3, kh = wid8 >> 2;
  if (blockIdx.x < 128) {
    const int g = blockIdx.x, bm = g >> 4, bn = g & 15;
    const int row0 = bm * 64 + (wid >> 1) * 32;
    const int col0 = bn * 64 + (wid & 1) * 32;
    f32x4 ar[2][2], az[2][2], an[2][2];
    ZACC(ar); ZACC(az); ZACC(an);
    const u16* Asrc = (kh == 0) ? xg : bprev;
    const u16* W = (kh == 0) ? wih : whh;
    const u16* A0 = Asrc + (row0 + r16) * NBEL + kq * 8;
    const u16* A1 = A0 + 16 * NBEL;
    const u16* Br0 = W + (size_t)(col0 + r16) * NBEL + kq * 8;
    const u16* Br1 = Br0 + 16 * NBEL;
    const u16* Bz0 = W + (size_t)(col0 + 1024 + r16) * NBEL + kq * 8;
    const u16* Bz1 = Bz0 + 16 * NBEL;
    const u16* Bn0 = W + (size_t)(col0 + 2048 + r16) * NBEL + kq * 8;
    const u16* Bn1 = Bn0 + 16 * NBEL;
#pragma unroll 4
    for (int k = 0; k < NBEL; k += 32) {
      bf16x8 a0 = ld8bf(A0 + k), a1 = ld8bf(A1 + k);
      bf16x8 b0 = ld8bf(Br0 + k), b1 = ld8bf(Br1 + k);
      Q4(ar, a0, a1, b0, b1);
      bf16x8 c0 = ld8bf(Bz0 + k), c1 = ld8bf(Bz1 + k);
      Q4(az, a0, a1, c0, c1);
      bf16x8 d0 = ld8bf(Bn0 + k), d1 = ld8bf(Bn1 + k);
      Q4(an, a0, a1, d0, d1);
    }
    if (kh == 1) {
      red_write(&lred[wid][0][0], ar, l);
      red_write(&lred[wid][1][0], az, l);
      red_write(&lred[wid][2][0], an, l);
    }
    __syncthreads();
    if (kh == 0) {
      const int base = l * 16;
#pragma unroll
      for (int i = 0; i < 2; ++i)
#pragma unroll
        for (int j = 0; j < 2; ++j)
#pragma unroll
          for (int q = 0; q < 4; ++q) {
            const int row = row0 + i * 16 + kq * 4 + q;
            const int c = col0 + j * 16 + r16;
            const int li = base + (i * 2 + j) * 4 + q;
            const float r = sigm(ar[i][j][q] + bih[c] + lred[wid][0][li] + bhh[c]);
            const float z = sigm(az[i][j][q] + bih[c + 1024] + lred[wid][1][li] + bhh[c + 1024]);
            const float n = tanhf(an[i][j][q] + bih[c + 2048] +
                                  r * (lred[wid][2][li] + bhh[c + 2048]));
            const float h = hf[row * NBEL + c];
            const float bnew = (1.f - z) * n + z * h;
            hf[row * NBEL + c] = bnew;
            bcur[row * NBEL + c] = f2bf(bnew);
            out[OUT_B + (size_t)t * (NB * NBEL) + row * NBEL + c] = bnew;
          }
    }
  } else if (t >= 1) {
    dev_spri(blockIdx.x - 128, wid, kh, r16, kq, l, t - 1,
             hpri, wspri, bspri, npri, out,
             &lred[wid][0][0], &lred[wid][1][0]);
  }
}

// ======================= kL2: hbB(t) [0..127] | bpri(t) [128..255] | hbO(t+1) [256..383] =======================
__global__ __launch_bounds__(512, 2) void kL2(
    const u16* __restrict__ bcur, const u16* __restrict__ wbpos,
    const float* __restrict__ bbpos, const float* __restrict__ hbOc,
    u16* __restrict__ hbbf,
    const u16* __restrict__ wbpri, const float* __restrict__ bbpri,
    u16* __restrict__ hpri,
    const float* __restrict__ Of, float* __restrict__ hbOn, int t) {
  __shared__ float lred[4][1024];
  const int l = threadIdx.x & 63, r16 = l & 15, kq = l >> 4;
  const int wid8 = threadIdx.x >> 6;
  const int wid = wid8 & 3, kh = wid8 >> 2;
  if (blockIdx.x < 128) {
    const int g = blockIdx.x, bm = g >> 4, bn = g & 15;
    const int row0 = bm * 64 + (wid >> 1) * 32;
    const int col0 = bn * 64 + (wid & 1) * 32;
    f32x4 acc[2][2]; ZACC(acc);
    const u16* A0 = bcur + (row0 + r16) * NBEL + kh * 512 + kq * 8;
    const u16* A1 = A0 + 16 * NBEL;
    const u16* B0 = wbpos + (size_t)(col0 + r16) * 2048 + kh * 512 + kq * 8;
    const u16* B1 = B0 + 16 * 2048;
#pragma unroll 4
    for (int k = 0; k < 512; k += 32) {
      bf16x8 a0 = ld8bf(A0 + k), a1 = ld8bf(A1 + k);
      bf16x8 b0 = ld8bf(B0 + k), b1 = ld8bf(B1 + k);
      Q4(acc, a0, a1, b0, b1);
    }
    if (kh == 1) red_write(lred[wid], acc, l);
    __syncthreads();
    if (kh == 0) {
      red_add(lred[wid], acc, l);
#pragma unroll
      for (int i = 0; i < 2; ++i)
#pragma unroll
        for (int j = 0; j < 2; ++j)
#pragma unroll
          for (int q = 0; q < 4; ++q) {
            const int row = row0 + i * 16 + kq * 4 + q;
            const int col = col0 + j * 16 + r16;
            const float v = acc[i][j][q] + hbOc[row * NBEL + col] + bbpos[col];
            hbbf[row * NBEL + col] = f2bf(fmaxf(v, 0.f));
          }
    }
  } else if (blockIdx.x < 256) {
    const int g = blockIdx.x - 128, bm = g >> 4, bn = g & 15;
    const int row0 = bm * 64 + (wid >> 1) * 32;
    const int col0 = bn * 64 + (wid & 1) * 32;
    f32x4 acc[2][2]; ZACC(acc);
    const u16* A0 = bcur + (row0 + r16) * NBEL + kh * 512 + kq * 8;
    const u16* A1 = A0 + 16 * NBEL;
    const u16* B0 = wbpri + (size_t)(col0 + r16) * NBEL + kh * 512 + kq * 8;
    const u16* B1 = B0 + 16 * NBEL;
#pragma unroll 4
    for (int k = 0; k < 512; k += 32) {
      bf16x8 a0 = ld8bf(A0 + k), a1 = ld8bf(A1 + k);
      bf16x8 b0 = ld8bf(B0 + k), b1 = ld8bf(B1 + k);
      Q4(acc, a0, a1, b0, b1);
    }
    if (kh == 1) red_write(lred[wid], acc, l);
    __syncthreads();
    if (kh == 0) {
      red_add(lred[wid], acc, l);
#pragma unroll
      for (int i = 0; i < 2; ++i)
#pragma unroll
        for (int j = 0; j < 2; ++j)
#pragma unroll
          for (int q = 0; q < 4; ++q) {
            const int row = row0 + i * 16 + kq * 4 + q;
            const int col = col0 + j * 16 + r16;
            hpri[row * NBEL + col] = f2bf(fmaxf(acc[i][j][q] + bbpri[col], 0.f));
          }
    }
  } else {
    if (t + 1 >= NT) return;
    const int g = blockIdx.x - 256, bm = g >> 4, bn = g & 15;
    const int row0 = bm * 64 + (wid >> 1) * 32;
    const int col0 = bn * 64 + (wid & 1) * 32;
    f32x4 acc[2][2]; ZACC(acc);
    const float* F0 = Of + (size_t)(t + 1) * (NB * NBEL) + (row0 + r16) * NBEL + kh * 512 + kq * 8;
    const float* F1 = F0 + 16 * NBEL;
    const u16* B0 = wbpos + (size_t)(col0 + r16) * 2048 + 1024 + kh * 512 + kq * 8;
    const u16* B1 = B0 + 16 * 2048;
#pragma unroll 4
    for (int k = 0; k < 512; k += 32) {
      bf16x8 a0 = cvt8(F0 + k), a1 = cvt8(F1 + k);
      bf16x8 b0 = ld8bf(B0 + k), b1 = ld8bf(B1 + k);
      Q4(acc, a0, a1, b0, b1);
    }
    if (kh == 1) red_write(lred[wid], acc, l);
    __syncthreads();
    if (kh == 0) {
      red_add(lred[wid], acc, l);
#pragma unroll
      for (int i = 0; i < 2; ++i)
#pragma unroll
        for (int j = 0; j < 2; ++j)
#pragma unroll
          for (int q = 0; q < 4; ++q) {
            const int row = row0 + i * 16 + kq * 4 + q;
            const int col = col0 + j * 16 + r16;
            hbOn[row * NBEL + col] = acc[i][j][q];
          }
    }
  }
}

// ======================= kL3: sposx row-local [0..15] | spri(63) [16..47] =======================
// block b (<16) owns batch rows [32b, 32b+32):
//   phase S: spos(t) for those rows (K=1024 over hbbf rows) -> outputs + smask in LDS
//   phase X: x(t+1) for those rows (K=256 LDS smask + K=64 Af) -> xg
__global__ __launch_bounds__(512, 1) void kL3(
    const u16* __restrict__ hbbf, const u16* __restrict__ wspos,
    const float* __restrict__ bspos, const float* __restrict__ npos,
    const float* __restrict__ Mptr, float* __restrict__ out,
    const float* __restrict__ Af, const u16* __restrict__ wsa,
    const float* __restrict__ bsa, u16* __restrict__ xg,
    const u16* __restrict__ hpri, const u16* __restrict__ wspri,
    const float* __restrict__ bspri, const float* __restrict__ npri, int t) {
  const int l = threadIdx.x & 63, r16 = l & 15, kq = l >> 4;
  const int wid8 = threadIdx.x >> 6;
  if (blockIdx.x >= 16) {
    if (t == NT - 1) {
      __shared__ float lredS[4][2][1024];
      const int wid = wid8 & 3, kh = wid8 >> 2;
      dev_spri(blockIdx.x - 16, wid, kh, r16, kq, l, NT - 1,
               hpri, wspri, bspri, npri, out,
               &lredS[wid][0][0], &lredS[wid][1][0]);
    }
    return;
  }
  __shared__ float stg[2][32][260];   // mu, hp staging (~66.6KB)
  __shared__ u16 sm[32][264];         // smask bf16 (~16.9KB)
  const int rb = blockIdx.x * 32;
  // ---- phase S: spos GEMM ----
  const int gem = wid8 >> 2, ct = wid8 & 3;   // gem: 0=mu 1=hp; cols 64*ct..+63
#pragma unroll
  for (int jt = 0; jt < 2; ++jt) {
    const int c0 = ct * 64 + jt * 32;
    f32x4 acc[2][2]; ZACC(acc);
    const u16* A0 = hbbf + (size_t)(rb + r16) * NBEL + kq * 8;
    const u16* A1 = A0 + 16 * NBEL;
    const u16* B0 = wspos + (size_t)(gem * 256 + c0 + r16) * NBEL + kq * 8;
    const u16* B1 = B0 + 16 * NBEL;
#pragma unroll 4
    for (int k = 0; k < NBEL; k += 32) {
      bf16x8 a0 = ld8bf(A0 + k), a1 = ld8bf(A1 + k);
      bf16x8 b0 = ld8bf(B0 + k), b1 = ld8bf(B1 + k);
      Q4(acc, a0, a1, b0, b1);
    }
#pragma unroll
    for (int i = 0; i < 2; ++i)
#pragma unroll
      for (int j = 0; j < 2; ++j)
#pragma unroll
        for (int q = 0; q < 4; ++q)
          stg[gem][i * 16 + kq * 4 + q][c0 + j * 16 + r16] = acc[i][j][q];
  }
  __syncthreads();
  // ---- sample + smask into LDS ----
  {
    const int rr = threadIdx.x >> 4;          // 0..31
    const int cb = (threadIdx.x & 15) * 16;   // 0..240
    const int row = rb + rr;
    const float mn = (t < NT - 1) ? Mptr[(t + 1) * NB + row] : 1.f;
#pragma unroll 4
    for (int e = 0; e < 16; ++e) {
      const int c = cb + e;
      const float mu = stg[0][rr][c] + bspos[c];
      const float hq = stg[1][rr][c] + bspos[c + 256];
      const float sd = softplus_(hq) + 0.1f;
      const size_t idx = (size_t)t * (NB * NS) + (size_t)row * NS + c;
      const float sq = mu + sd * npos[idx];
      out[OUT_SPOS + idx] = sq;
      out[OUT_MUPOS + idx] = mu;
      out[OUT_STDPOS + idx] = sd;
      sm[rr][c] = f2bf(sq * mn);
    }
  }
  __syncthreads();
  // ---- phase X: x(t+1) ----
  if (t + 1 < NT) {
#pragma unroll
    for (int jt = 0; jt < 4; ++jt) {
      const int c0 = wid8 * 128 + jt * 32;
      f32x4 acc[2][2]; ZACC(acc);
      const u16* B0 = wsa + (size_t)(c0 + r16) * 320 + kq * 8;
      const u16* B1 = B0 + 16 * 320;
#pragma unroll
      for (int k = 0; k < 256; k += 32) {
        bf16x8 a0 = *(const bf16x8*)&sm[r16][k + kq * 8];
        bf16x8 a1 = *(const bf16x8*)&sm[16 + r16][k + kq * 8];
        bf16x8 b0 = ld8bf(B0 + k), b1 = ld8bf(B1 + k);
        Q4(acc, a0, a1, b0, b1);
      }
      const float* F0 = Af + (size_t)(t + 1) * (NB * NA) + (size_t)(rb + r16) * NA + kq * 8;
      const float* F1 = F0 + 16 * NA;
      const u16* C0 = wsa + (size_t)(c0 + r16) * 320 + 256 + kq * 8;
      const u16* C1 = C0 + 16 * 320;
#pragma unroll
      for (int k = 0; k < 64; k += 32) {
        bf16x8 a0 = cvt8(F0 + k), a1 = cvt8(F1 + k);
        bf16x8 b0 = ld8bf(C0 + k), b1 = ld8bf(C1 + k);
        Q4(acc, a0, a1, b0, b1);
      }
#pragma unroll
      for (int i = 0; i < 2; ++i)
#pragma unroll
        for (int j = 0; j < 2; ++j)
#pragma unroll
          for (int q = 0; q < 4; ++q) {
            const int row = rb + i * 16 + kq * 4 + q;
            const int col = c0 + j * 16 + r16;
            xg[row * NBEL + col] = f2bf(fmaxf(acc[i][j][q] + bsa[col], 0.f));
          }
    }
  }
}

extern "C" void kernel_launch(void* const* d_in, const int* in_sizes, int n_in,
                              void* d_out, int out_size, void* d_ws, size_t ws_size,
                              hipStream_t stream) {
  const float* s0 = (const float*)d_in[0];
  const float* Af = (const float*)d_in[1];
  const float* b0 = (const float*)d_in[2];
  const float* Of = (const float*)d_in[3];
  const float* Mp = (const float*)d_in[4];
  const float* npri = (const float*)d_in[5];
  const float* npos = (const float*)d_in[6];
  const float* Wsa = (const float*)d_in[7];
  const float* bsa = (const float*)d_in[8];
  const float* Wih = (const float*)d_in[9];
  const float* bih = (const float*)d_in[10];
  const float* Whh = (const float*)d_in[11];
  const float* bhh = (const float*)d_in[12];
  const float* Wbpri = (const float*)d_in[13];
  const float* bbpri = (const float*)d_in[14];
  const float* Wspri = (const float*)d_in[15];
  const float* bspri = (const float*)d_in[16];
  const float* Wbpos = (const float*)d_in[17];
  const float* bbpos = (const float*)d_in[18];
  const float* Wspos = (const float*)d_in[19];
  const float* bspos = (const float*)d_in[20];

  float* out = (float*)d_out;
  char* ws = (char*)d_ws;
  u16* wbase   = (u16*)ws;
  u16* wsa_b   = wbase;
  u16* wih_b   = wbase + 327680;
  u16* whh_b   = wbase + 3473408;
  u16* wbpri_b = wbase + 6619136;
  u16* wspri_b = wbase + 7667712;
  u16* wbpos_b = wbase + 8192000;
  u16* wspos_b = wbase + 10289152;
  // weights end at byte 21,626,880
  u16*   smask = (u16*)  (ws + 21626880);  // [512,256]  bf16 (t=0 only)
  u16*   bbf0  = (u16*)  (ws + 21889024);  // [512,1024] bf16
  u16*   bbf1  = (u16*)  (ws + 22937600);  // [512,1024] bf16
  float* hf    = (float*)(ws + 23986176);  // [512,1024] f32
  u16*   xg    = (u16*)  (ws + 26083328);  // [512,1024] bf16
  float* hbO0  = (float*)(ws + 27131904);  // [512,1024] f32
  float* hbO1  = (float*)(ws + 29229056);  // [512,1024] f32
  u16*   hbbf  = (u16*)  (ws + 31326208);  // [512,1024] bf16
  u16*   hpri  = (u16*)  (ws + 32374784);  // [512,1024] bf16
  // ws end: 33,423,360 bytes

  cvt_weights_k<<<2048, 256, 0, stream>>>(Wsa, Wih, Whh, Wbpri, Wspri, Wbpos,
                                          Wspos, wbase);
  init_carry_k<<<2048, 256, 0, stream>>>(s0, b0, Mp, smask, bbf0, hf);
  kX0<<<256, 512, 0, stream>>>(smask, Af, wsa_b, bsa, xg, Of, wbpos_b, hbO0);

  for (int t = 0; t < NT; ++t) {
    const u16* bprev = (t & 1) ? bbf1 : bbf0;
    u16* bcur = (t & 1) ? bbf0 : bbf1;
    float* hbOc = (t & 1) ? hbO1 : hbO0;
    float* hbOn = (t & 1) ? hbO0 : hbO1;
    kL1<<<160, 512, 0, stream>>>(xg, bprev, wih_b, whh_b, bih, bhh, hf, bcur,
                                 out, hpri, wspri_b, bspri, npri, t);
    kL2<<<384, 512, 0, stream>>>(bcur, wbpos_b, bbpos, hbOc, hbbf,
                                 wbpri_b, bbpri, hpri, Of, hbOn, t);
    kL3<<<48, 512, 0, stream>>>(hbbf, wspos_b, bspos, npos, Mp, out,
                                Af, wsa_b, bsa, xg,
                                hpri, wspri_b, bspri, npri, t);
  }
}

// Round 10
// 9406.429 us; speedup vs baseline: 1.7369x; 1.4395x over previous
//
#include <hip/hip_runtime.h>
#include <hip/hip_bf16.h>
#include <math.h>

typedef short bf16x8 __attribute__((ext_vector_type(8)));
typedef float f32x4 __attribute__((ext_vector_type(4)));
typedef unsigned short u16;

#define NT 64
#define NB 512
#define NS 256
#define NA 64
#define NBEL 1024

// d_out element offsets (f32 elements)
#define OUT_B      0
#define OUT_SPRI   33554432
#define OUT_MUPRI  41943040
#define OUT_STDPRI 50331648
#define OUT_SPOS   58720256
#define OUT_MUPOS  67108864
#define OUT_STDPOS 75497472

__device__ __forceinline__ f32x4 mfma16(bf16x8 a, bf16x8 b, f32x4 c) {
  return __builtin_amdgcn_mfma_f32_16x16x32_bf16(a, b, c, 0, 0, 0);
}

__device__ __forceinline__ u16 f2bf(float f) {
  union { float f; unsigned u; } v; v.f = f;
  return (u16)((v.u + 0x7FFFu + ((v.u >> 16) & 1u)) >> 16);
}

__device__ __forceinline__ bf16x8 ld8bf(const u16* p) { return *(const bf16x8*)p; }

__device__ __forceinline__ bf16x8 cvt8(const float* p) {
  const float4 lo = *(const float4*)p;
  const float4 hi = *(const float4*)(p + 4);
  bf16x8 v;
  v[0] = (short)f2bf(lo.x); v[1] = (short)f2bf(lo.y);
  v[2] = (short)f2bf(lo.z); v[3] = (short)f2bf(lo.w);
  v[4] = (short)f2bf(hi.x); v[5] = (short)f2bf(hi.y);
  v[6] = (short)f2bf(hi.z); v[7] = (short)f2bf(hi.w);
  return v;
}

__device__ __forceinline__ float sigm(float x) { return 1.f / (1.f + __expf(-x)); }
__device__ __forceinline__ float softplus_(float x) {
  if (x > 20.f) return x;
  return log1pf(__expf(x));
}

#define ZACC(acc) { acc[0][0] = (f32x4){0.f,0.f,0.f,0.f}; acc[0][1] = (f32x4){0.f,0.f,0.f,0.f}; \
                    acc[1][0] = (f32x4){0.f,0.f,0.f,0.f}; acc[1][1] = (f32x4){0.f,0.f,0.f,0.f}; }

#define Q4(acc, a0v, a1v, b0v, b1v) \
  acc[0][0] = mfma16(a0v, b0v, acc[0][0]); \
  acc[0][1] = mfma16(a0v, b1v, acc[0][1]); \
  acc[1][0] = mfma16(a1v, b0v, acc[1][0]); \
  acc[1][1] = mfma16(a1v, b1v, acc[1][1]);

__device__ __forceinline__ void red_write(float* L, f32x4 (&acc)[2][2], int l) {
  const int base = l * 16;
#pragma unroll
  for (int i = 0; i < 2; ++i)
#pragma unroll
    for (int j = 0; j < 2; ++j)
#pragma unroll
      for (int q = 0; q < 4; ++q)
        L[base + (i * 2 + j) * 4 + q] = acc[i][j][q];
}
__device__ __forceinline__ void red_add(const float* L, f32x4 (&acc)[2][2], int l) {
  const int base = l * 16;
#pragma unroll
  for (int i = 0; i < 2; ++i)
#pragma unroll
    for (int j = 0; j < 2; ++j)
#pragma unroll
      for (int q = 0; q < 4; ++q)
        acc[i][j][q] += L[base + (i * 2 + j) * 4 + q];
}

// -------- device-scope flag sync (proven in R7/R8 scans) --------
__device__ __forceinline__ void setflag_blk(unsigned* f) {
  __syncthreads();
  if (threadIdx.x == 0)
    __hip_atomic_fetch_add(f, 1u, __ATOMIC_RELEASE, __HIP_MEMORY_SCOPE_AGENT);
}
__device__ __forceinline__ void waitflag_blk(unsigned* f, unsigned target) {
  if (threadIdx.x == 0) {
    while (__hip_atomic_load(f, __ATOMIC_RELAXED, __HIP_MEMORY_SCOPE_AGENT) < target)
      __builtin_amdgcn_s_sleep(2);
    (void)__hip_atomic_load(f, __ATOMIC_ACQUIRE, __HIP_MEMORY_SCOPE_AGENT);
  }
  __syncthreads();
}

// -------- P0: weights f32 -> bf16 --------
__global__ __launch_bounds__(256) void cvt_weights_k(
    const float* __restrict__ wsa, const float* __restrict__ wih,
    const float* __restrict__ whh, const float* __restrict__ wbpri,
    const float* __restrict__ wspri, const float* __restrict__ wbpos,
    const float* __restrict__ wspos, u16* __restrict__ dst) {
  const int S0 = 327680;
  const int S1 = S0 + 3145728;
  const int S2 = S1 + 3145728;
  const int S3 = S2 + 1048576;
  const int S4 = S3 + 524288;
  const int S5 = S4 + 2097152;
  const int S6 = S5 + 524288;
  for (int i = blockIdx.x * blockDim.x + threadIdx.x; i < S6;
       i += gridDim.x * blockDim.x) {
    float v;
    if (i < S0) v = wsa[i];
    else if (i < S1) v = wih[i - S0];
    else if (i < S2) v = whh[i - S1];
    else if (i < S3) v = wbpri[i - S2];
    else if (i < S4) v = wspri[i - S3];
    else if (i < S5) v = wbpos[i - S4];
    else v = wspos[i - S5];
    dst[i] = f2bf(v);
  }
}

// -------- P1: init carries + zero flags --------
__global__ __launch_bounds__(256) void init_carry_k(
    const float* __restrict__ s0, const float* __restrict__ b0,
    const float* __restrict__ Mptr, u16* __restrict__ smask,
    u16* __restrict__ bbf0, float* __restrict__ hf,
    unsigned* __restrict__ flags) {
  for (int i = blockIdx.x * blockDim.x + threadIdx.x; i < NB * NBEL;
       i += gridDim.x * blockDim.x) {
    float b = b0[i];
    bbf0[i] = f2bf(b);
    hf[i] = b;
    if (i < NB * NS) {
      int row = i >> 8;
      smask[i] = f2bf(s0[i] * Mptr[row]);
    }
    if (i < NT) flags[i] = 0;
  }
}

// -------- spri device piece: 32 blocks (8 x 4), K-split 8-wave --------
__device__ __forceinline__ void dev_spri(
    int g, int wid, int kh, int r16, int kq, int l, int tt,
    const u16* __restrict__ hpri, const u16* __restrict__ wspri,
    const float* __restrict__ bspri, const float* __restrict__ npri,
    float* __restrict__ out, float* lred0, float* lred1) {
  const int bm = g >> 2, bn = g & 3;
  const int row0 = bm * 64 + (wid >> 1) * 32;
  const int c0 = bn * 64 + (wid & 1) * 32;
  f32x4 am[2][2], ah[2][2];
  ZACC(am); ZACC(ah);
  const u16* A0 = hpri + (row0 + r16) * NBEL + kh * 512 + kq * 8;
  const u16* A1 = A0 + 16 * NBEL;
  const u16* Bm0 = wspri + (size_t)(c0 + r16) * NBEL + kh * 512 + kq * 8;
  const u16* Bm1 = Bm0 + 16 * NBEL;
  const u16* Bh0 = wspri + (size_t)(c0 + 256 + r16) * NBEL + kh * 512 + kq * 8;
  const u16* Bh1 = Bh0 + 16 * NBEL;
#pragma unroll 4
  for (int k = 0; k < 512; k += 32) {
    bf16x8 a0 = ld8bf(A0 + k), a1 = ld8bf(A1 + k);
    bf16x8 m0 = ld8bf(Bm0 + k), m1 = ld8bf(Bm1 + k);
    Q4(am, a0, a1, m0, m1);
    bf16x8 h0 = ld8bf(Bh0 + k), h1 = ld8bf(Bh1 + k);
    Q4(ah, a0, a1, h0, h1);
  }
  if (kh == 1) {
    red_write(lred0, am, l);
    red_write(lred1, ah, l);
  }
  __syncthreads();
  if (kh == 0) {
    red_add(lred0, am, l);
    red_add(lred1, ah, l);
#pragma unroll
    for (int i = 0; i < 2; ++i)
#pragma unroll
      for (int j = 0; j < 2; ++j)
#pragma unroll
        for (int q = 0; q < 4; ++q) {
          const int row = row0 + i * 16 + kq * 4 + q;
          const int c = c0 + j * 16 + r16;
          const size_t idx = (size_t)tt * (NB * NS) + (size_t)row * NS + c;
          const float mu = am[i][j][q] + bspri[c];
          const float hp = ah[i][j][q] + bspri[c + 256];
          const float sd = softplus_(hp) + 0.1f;
          out[OUT_SPRI + idx] = mu + sd * npri[idx];
          out[OUT_MUPRI + idx] = mu;
          out[OUT_STDPRI + idx] = sd;
        }
  }
}

// -------- x device piece: 128 blocks (8 x 16), K=320 split over 8 waves --------
__device__ __forceinline__ void dev_x(
    int g, int wid, int kh, int r16, int kq, int l, int t,
    const u16* __restrict__ smask, const float* __restrict__ Af,
    const u16* __restrict__ wsa, const float* __restrict__ bsa,
    u16* __restrict__ xg, float* lred) {
  const int bm = g >> 4, bn = g & 15;
  const int row0 = bm * 64 + (wid >> 1) * 32;
  const int col0 = bn * 64 + (wid & 1) * 32;
  f32x4 acc[2][2]; ZACC(acc);
  const u16* A0 = smask + (row0 + r16) * NS + kq * 8;
  const u16* A1 = A0 + 16 * NS;
  const u16* B0 = wsa + (size_t)(col0 + r16) * 320 + kq * 8;
  const u16* B1 = B0 + 16 * 320;
  if (kh == 0) {
#pragma unroll
    for (int k = 0; k < 160; k += 32) {
      bf16x8 a0 = ld8bf(A0 + k), a1 = ld8bf(A1 + k);
      bf16x8 b0 = ld8bf(B0 + k), b1 = ld8bf(B1 + k);
      Q4(acc, a0, a1, b0, b1);
    }
  } else {
#pragma unroll
    for (int k = 160; k < 256; k += 32) {
      bf16x8 a0 = ld8bf(A0 + k), a1 = ld8bf(A1 + k);
      bf16x8 b0 = ld8bf(B0 + k), b1 = ld8bf(B1 + k);
      Q4(acc, a0, a1, b0, b1);
    }
    const float* F0 = Af + (size_t)t * (NB * NA) + (size_t)(row0 + r16) * NA + kq * 8;
    const float* F1 = F0 + 16 * NA;
    const u16* C0 = wsa + (size_t)(col0 + r16) * 320 + 256 + kq * 8;
    const u16* C1 = C0 + 16 * 320;
#pragma unroll
    for (int k = 0; k < 64; k += 32) {
      bf16x8 a0 = cvt8(F0 + k), a1 = cvt8(F1 + k);
      bf16x8 b0 = ld8bf(C0 + k), b1 = ld8bf(C1 + k);
      Q4(acc, a0, a1, b0, b1);
    }
    red_write(lred, acc, l);
  }
  __syncthreads();
  if (kh == 0) {
    red_add(lred, acc, l);
#pragma unroll
    for (int i = 0; i < 2; ++i)
#pragma unroll
      for (int j = 0; j < 2; ++j)
#pragma unroll
        for (int q = 0; q < 4; ++q) {
          const int row = row0 + i * 16 + kq * 4 + q;
          const int col = col0 + j * 16 + r16;
          xg[row * NBEL + col] = f2bf(fmaxf(acc[i][j][q] + bsa[col], 0.f));
        }
  }
}

// ======================= kX0: x(0) [0..127] | hbO(0) [128..255] =======================
__global__ __launch_bounds__(512, 2) void kX0(
    const u16* __restrict__ smask, const float* __restrict__ Af,
    const u16* __restrict__ wsa, const float* __restrict__ bsa,
    u16* __restrict__ xg, const float* __restrict__ Of,
    const u16* __restrict__ wbpos, float* __restrict__ hbO0) {
  __shared__ float lred[4][1024];
  const int l = threadIdx.x & 63, r16 = l & 15, kq = l >> 4;
  const int wid8 = threadIdx.x >> 6;
  const int wid = wid8 & 3, kh = wid8 >> 2;
  if (blockIdx.x < 128) {
    dev_x(blockIdx.x, wid, kh, r16, kq, l, 0, smask, Af, wsa, bsa, xg,
          lred[wid]);
  } else {
    const int g = blockIdx.x - 128, bm = g >> 4, bn = g & 15;
    const int row0 = bm * 64 + (wid >> 1) * 32;
    const int col0 = bn * 64 + (wid & 1) * 32;
    f32x4 acc[2][2]; ZACC(acc);
    const float* F0 = Of + (row0 + r16) * NBEL + kh * 512 + kq * 8;
    const float* F1 = F0 + 16 * NBEL;
    const u16* B0 = wbpos + (size_t)(col0 + r16) * 2048 + 1024 + kh * 512 + kq * 8;
    const u16* B1 = B0 + 16 * 2048;
#pragma unroll 4
    for (int k = 0; k < 512; k += 32) {
      bf16x8 a0 = cvt8(F0 + k), a1 = cvt8(F1 + k);
      bf16x8 b0 = ld8bf(B0 + k), b1 = ld8bf(B1 + k);
      Q4(acc, a0, a1, b0, b1);
    }
    if (kh == 1) red_write(lred[wid], acc, l);
    __syncthreads();
    if (kh == 0) {
      red_add(lred[wid], acc, l);
#pragma unroll
      for (int i = 0; i < 2; ++i)
#pragma unroll
        for (int j = 0; j < 2; ++j)
#pragma unroll
          for (int q = 0; q < 4; ++q) {
            const int row = row0 + i * 16 + kq * 4 + q;
            const int col = col0 + j * 16 + r16;
            hbO0[row * NBEL + col] = acc[i][j][q];
          }
    }
  }
}

// ======================= kL1: gi+gh+GRU [0..127] | spri(t-1) [128..159] =======================
__global__ __launch_bounds__(512, 2) void kL1(
    const u16* __restrict__ xg, const u16* __restrict__ bprev,
    const u16* __restrict__ wih, const u16* __restrict__ whh,
    const float* __restrict__ bih, const float* __restrict__ bhh,
    float* __restrict__ hf, u16* __restrict__ bcur, float* __restrict__ out,
    const u16* __restrict__ hpri, const u16* __restrict__ wspri,
    const float* __restrict__ bspri, const float* __restrict__ npri, int t) {
  __shared__ float lred[4][3][1024];  // 48KB
  const int l = threadIdx.x & 63, r16 = l & 15, kq = l >> 4;
  const int wid8 = threadIdx.x >> 6;
  const int wid = wid8 & 3, kh = wid8 >> 2;
  if (blockIdx.x < 128) {
    const int g = blockIdx.x, bm = g >> 4, bn = g & 15;
    const int row0 = bm * 64 + (wid >> 1) * 32;
    const int col0 = bn * 64 + (wid & 1) * 32;
    f32x4 ar[2][2], az[2][2], an[2][2];
    ZACC(ar); ZACC(az); ZACC(an);
    const u16* Asrc = (kh == 0) ? xg : bprev;
    const u16* W = (kh == 0) ? wih : whh;
    const u16* A0 = Asrc + (row0 + r16) * NBEL + kq * 8;
    const u16* A1 = A0 + 16 * NBEL;
    const u16* Br0 = W + (size_t)(col0 + r16) * NBEL + kq * 8;
    const u16* Br1 = Br0 + 16 * NBEL;
    const u16* Bz0 = W + (size_t)(col0 + 1024 + r16) * NBEL + kq * 8;
    const u16* Bz1 = Bz0 + 16 * NBEL;
    const u16* Bn0 = W + (size_t)(col0 + 2048 + r16) * NBEL + kq * 8;
    const u16* Bn1 = Bn0 + 16 * NBEL;
#pragma unroll 4
    for (int k = 0; k < NBEL; k += 32) {
      bf16x8 a0 = ld8bf(A0 + k), a1 = ld8bf(A1 + k);
      bf16x8 b0 = ld8bf(Br0 + k), b1 = ld8bf(Br1 + k);
      Q4(ar, a0, a1, b0, b1);
      bf16x8 c0 = ld8bf(Bz0 + k), c1 = ld8bf(Bz1 + k);
      Q4(az, a0, a1, c0, c1);
      bf16x8 d0 = ld8bf(Bn0 + k), d1 = ld8bf(Bn1 + k);
      Q4(an, a0, a1, d0, d1);
    }
    if (kh == 1) {
      red_write(&lred[wid][0][0], ar, l);
      red_write(&lred[wid][1][0], az, l);
      red_write(&lred[wid][2][0], an, l);
    }
    __syncthreads();
    if (kh == 0) {
      const int base = l * 16;
#pragma unroll
      for (int i = 0; i < 2; ++i)
#pragma unroll
        for (int j = 0; j < 2; ++j)
#pragma unroll
          for (int q = 0; q < 4; ++q) {
            const int row = row0 + i * 16 + kq * 4 + q;
            const int c = col0 + j * 16 + r16;
            const int li = base + (i * 2 + j) * 4 + q;
            const float r = sigm(ar[i][j][q] + bih[c] + lred[wid][0][li] + bhh[c]);
            const float z = sigm(az[i][j][q] + bih[c + 1024] + lred[wid][1][li] + bhh[c + 1024]);
            const float n = tanhf(an[i][j][q] + bih[c + 2048] +
                                  r * (lred[wid][2][li] + bhh[c + 2048]));
            const float h = hf[row * NBEL + c];
            const float bnew = (1.f - z) * n + z * h;
            hf[row * NBEL + c] = bnew;
            bcur[row * NBEL + c] = f2bf(bnew);
            out[OUT_B + (size_t)t * (NB * NBEL) + row * NBEL + c] = bnew;
          }
    }
  } else if (t >= 1) {
    dev_spri(blockIdx.x - 128, wid, kh, r16, kq, l, t - 1,
             hpri, wspri, bspri, npri, out,
             &lred[wid][0][0], &lred[wid][1][0]);
  }
}

// ======================= kL2: hbB(t) [0..127] | bpri(t) [128..255] | hbO(t+1) [256..383] =======================
__global__ __launch_bounds__(512, 2) void kL2(
    const u16* __restrict__ bcur, const u16* __restrict__ wbpos,
    const float* __restrict__ bbpos, const float* __restrict__ hbOc,
    u16* __restrict__ hbbf,
    const u16* __restrict__ wbpri, const float* __restrict__ bbpri,
    u16* __restrict__ hpri,
    const float* __restrict__ Of, float* __restrict__ hbOn, int t) {
  __shared__ float lred[4][1024];
  const int l = threadIdx.x & 63, r16 = l & 15, kq = l >> 4;
  const int wid8 = threadIdx.x >> 6;
  const int wid = wid8 & 3, kh = wid8 >> 2;
  if (blockIdx.x < 128) {
    const int g = blockIdx.x, bm = g >> 4, bn = g & 15;
    const int row0 = bm * 64 + (wid >> 1) * 32;
    const int col0 = bn * 64 + (wid & 1) * 32;
    f32x4 acc[2][2]; ZACC(acc);
    const u16* A0 = bcur + (row0 + r16) * NBEL + kh * 512 + kq * 8;
    const u16* A1 = A0 + 16 * NBEL;
    const u16* B0 = wbpos + (size_t)(col0 + r16) * 2048 + kh * 512 + kq * 8;
    const u16* B1 = B0 + 16 * 2048;
#pragma unroll 4
    for (int k = 0; k < 512; k += 32) {
      bf16x8 a0 = ld8bf(A0 + k), a1 = ld8bf(A1 + k);
      bf16x8 b0 = ld8bf(B0 + k), b1 = ld8bf(B1 + k);
      Q4(acc, a0, a1, b0, b1);
    }
    if (kh == 1) red_write(lred[wid], acc, l);
    __syncthreads();
    if (kh == 0) {
      red_add(lred[wid], acc, l);
#pragma unroll
      for (int i = 0; i < 2; ++i)
#pragma unroll
        for (int j = 0; j < 2; ++j)
#pragma unroll
          for (int q = 0; q < 4; ++q) {
            const int row = row0 + i * 16 + kq * 4 + q;
            const int col = col0 + j * 16 + r16;
            const float v = acc[i][j][q] + hbOc[row * NBEL + col] + bbpos[col];
            hbbf[row * NBEL + col] = f2bf(fmaxf(v, 0.f));
          }
    }
  } else if (blockIdx.x < 256) {
    const int g = blockIdx.x - 128, bm = g >> 4, bn = g & 15;
    const int row0 = bm * 64 + (wid >> 1) * 32;
    const int col0 = bn * 64 + (wid & 1) * 32;
    f32x4 acc[2][2]; ZACC(acc);
    const u16* A0 = bcur + (row0 + r16) * NBEL + kh * 512 + kq * 8;
    const u16* A1 = A0 + 16 * NBEL;
    const u16* B0 = wbpri + (size_t)(col0 + r16) * NBEL + kh * 512 + kq * 8;
    const u16* B1 = B0 + 16 * NBEL;
#pragma unroll 4
    for (int k = 0; k < 512; k += 32) {
      bf16x8 a0 = ld8bf(A0 + k), a1 = ld8bf(A1 + k);
      bf16x8 b0 = ld8bf(B0 + k), b1 = ld8bf(B1 + k);
      Q4(acc, a0, a1, b0, b1);
    }
    if (kh == 1) red_write(lred[wid], acc, l);
    __syncthreads();
    if (kh == 0) {
      red_add(lred[wid], acc, l);
#pragma unroll
      for (int i = 0; i < 2; ++i)
#pragma unroll
        for (int j = 0; j < 2; ++j)
#pragma unroll
          for (int q = 0; q < 4; ++q) {
            const int row = row0 + i * 16 + kq * 4 + q;
            const int col = col0 + j * 16 + r16;
            hpri[row * NBEL + col] = f2bf(fmaxf(acc[i][j][q] + bbpri[col], 0.f));
          }
    }
  } else {
    if (t + 1 >= NT) return;
    const int g = blockIdx.x - 256, bm = g >> 4, bn = g & 15;
    const int row0 = bm * 64 + (wid >> 1) * 32;
    const int col0 = bn * 64 + (wid & 1) * 32;
    f32x4 acc[2][2]; ZACC(acc);
    const float* F0 = Of + (size_t)(t + 1) * (NB * NBEL) + (row0 + r16) * NBEL + kh * 512 + kq * 8;
    const float* F1 = F0 + 16 * NBEL;
    const u16* B0 = wbpos + (size_t)(col0 + r16) * 2048 + 1024 + kh * 512 + kq * 8;
    const u16* B1 = B0 + 16 * 2048;
#pragma unroll 4
    for (int k = 0; k < 512; k += 32) {
      bf16x8 a0 = cvt8(F0 + k), a1 = cvt8(F1 + k);
      bf16x8 b0 = ld8bf(B0 + k), b1 = ld8bf(B1 + k);
      Q4(acc, a0, a1, b0, b1);
    }
    if (kh == 1) red_write(lred[wid], acc, l);
    __syncthreads();
    if (kh == 0) {
      red_add(lred[wid], acc, l);
#pragma unroll
      for (int i = 0; i < 2; ++i)
#pragma unroll
        for (int j = 0; j < 2; ++j)
#pragma unroll
          for (int q = 0; q < 4; ++q) {
            const int row = row0 + i * 16 + kq * 4 + q;
            const int col = col0 + j * 16 + r16;
            hbOn[row * NBEL + col] = acc[i][j][q];
          }
    }
  }
}

// ======================= kLX: spos(t) [0..31] -> flag -> x(t+1) [32..159] | spri(63) [160..191] =======================
__global__ __launch_bounds__(512, 2) void kLX(
    const u16* __restrict__ hbbf, const u16* __restrict__ wspos,
    const float* __restrict__ bspos, const float* __restrict__ npos,
    const float* __restrict__ Mptr, float* __restrict__ out,
    u16* __restrict__ smask,
    const float* __restrict__ Af, const u16* __restrict__ wsa,
    const float* __restrict__ bsa, u16* __restrict__ xg,
    const u16* __restrict__ hpri, const u16* __restrict__ wspri,
    const float* __restrict__ bspri, const float* __restrict__ npri,
    unsigned* __restrict__ flags, int t) {
  __shared__ float lred[4][2][1024];  // 32KB
  const int l = threadIdx.x & 63, r16 = l & 15, kq = l >> 4;
  const int wid8 = threadIdx.x >> 6;
  const int wid = wid8 & 3, kh = wid8 >> 2;
  if (blockIdx.x < 32) {
    // ---- spos(t): R5-kD shape ----
    const int g = blockIdx.x, bm = g >> 2, bn = g & 3;
    const int row0 = bm * 64 + (wid >> 1) * 32;
    const int c0 = bn * 64 + (wid & 1) * 32;
    f32x4 am[2][2], ah[2][2];
    ZACC(am); ZACC(ah);
    const u16* A0 = hbbf + (row0 + r16) * NBEL + kh * 512 + kq * 8;
    const u16* A1 = A0 + 16 * NBEL;
    const u16* Bm0 = wspos + (size_t)(c0 + r16) * NBEL + kh * 512 + kq * 8;
    const u16* Bm1 = Bm0 + 16 * NBEL;
    const u16* Bh0 = wspos + (size_t)(c0 + 256 + r16) * NBEL + kh * 512 + kq * 8;
    const u16* Bh1 = Bh0 + 16 * NBEL;
#pragma unroll 4
    for (int k = 0; k < 512; k += 32) {
      bf16x8 a0 = ld8bf(A0 + k), a1 = ld8bf(A1 + k);
      bf16x8 m0 = ld8bf(Bm0 + k), m1 = ld8bf(Bm1 + k);
      Q4(am, a0, a1, m0, m1);
      bf16x8 h0 = ld8bf(Bh0 + k), h1 = ld8bf(Bh1 + k);
      Q4(ah, a0, a1, h0, h1);
    }
    if (kh == 1) {
      red_write(&lred[wid][0][0], am, l);
      red_write(&lred[wid][1][0], ah, l);
    }
    __syncthreads();
    if (kh == 0) {
      red_add(&lred[wid][0][0], am, l);
      red_add(&lred[wid][1][0], ah, l);
#pragma unroll
      for (int i = 0; i < 2; ++i)
#pragma unroll
        for (int j = 0; j < 2; ++j)
#pragma unroll
          for (int q = 0; q < 4; ++q) {
            const int row = row0 + i * 16 + kq * 4 + q;
            const int c = c0 + j * 16 + r16;
            const float mu = am[i][j][q] + bspos[c];
            const float hq = ah[i][j][q] + bspos[c + 256];
            const float sd = softplus_(hq) + 0.1f;
            const size_t idx = (size_t)t * (NB * NS) + (size_t)row * NS + c;
            const float sq = mu + sd * npos[idx];
            out[OUT_SPOS + idx] = sq;
            out[OUT_MUPOS + idx] = mu;
            out[OUT_STDPOS + idx] = sd;
            const float mn = (t < NT - 1) ? Mptr[(t + 1) * NB + row] : 1.f;
            smask[row * NS + c] = f2bf(sq * mn);
          }
    }
    setflag_blk(&flags[t]);
  } else if (blockIdx.x < 160) {
    // ---- x(t+1): waits for all 32 spos blocks ----
    if (t + 1 >= NT) return;
    waitflag_blk(&flags[t], 32);
    dev_x(blockIdx.x - 32, wid, kh, r16, kq, l, t + 1, smask, Af, wsa, bsa,
          xg, &lred[wid][0][0]);
  } else {
    // ---- spri(63) tail: hpri(63) was written by kL2(63) ----
    if (t == NT - 1)
      dev_spri(blockIdx.x - 160, wid, kh, r16, kq, l, t,
               hpri, wspri, bspri, npri, out,
               &lred[wid][0][0], &lred[wid][1][0]);
  }
}

extern "C" void kernel_launch(void* const* d_in, const int* in_sizes, int n_in,
                              void* d_out, int out_size, void* d_ws, size_t ws_size,
                              hipStream_t stream) {
  const float* s0 = (const float*)d_in[0];
  const float* Af = (const float*)d_in[1];
  const float* b0 = (const float*)d_in[2];
  const float* Of = (const float*)d_in[3];
  const float* Mp = (const float*)d_in[4];
  const float* npri = (const float*)d_in[5];
  const float* npos = (const float*)d_in[6];
  const float* Wsa = (const float*)d_in[7];
  const float* bsa = (const float*)d_in[8];
  const float* Wih = (const float*)d_in[9];
  const float* bih = (const float*)d_in[10];
  const float* Whh = (const float*)d_in[11];
  const float* bhh = (const float*)d_in[12];
  const float* Wbpri = (const float*)d_in[13];
  const float* bbpri = (const float*)d_in[14];
  const float* Wspri = (const float*)d_in[15];
  const float* bspri = (const float*)d_in[16];
  const float* Wbpos = (const float*)d_in[17];
  const float* bbpos = (const float*)d_in[18];
  const float* Wspos = (const float*)d_in[19];
  const float* bspos = (const float*)d_in[20];

  float* out = (float*)d_out;
  char* ws = (char*)d_ws;
  u16* wbase   = (u16*)ws;
  u16* wsa_b   = wbase;
  u16* wih_b   = wbase + 327680;
  u16* whh_b   = wbase + 3473408;
  u16* wbpri_b = wbase + 6619136;
  u16* wspri_b = wbase + 7667712;
  u16* wbpos_b = wbase + 8192000;
  u16* wspos_b = wbase + 10289152;
  // weights end at byte 21,626,880
  u16*   smask = (u16*)  (ws + 21626880);  // [512,256]  bf16
  u16*   bbf0  = (u16*)  (ws + 21889024);  // [512,1024] bf16
  u16*   bbf1  = (u16*)  (ws + 22937600);  // [512,1024] bf16
  float* hf    = (float*)(ws + 23986176);  // [512,1024] f32
  u16*   xg    = (u16*)  (ws + 26083328);  // [512,1024] bf16
  float* hbO0  = (float*)(ws + 27131904);  // [512,1024] f32
  float* hbO1  = (float*)(ws + 29229056);  // [512,1024] f32
  u16*   hbbf  = (u16*)  (ws + 31326208);  // [512,1024] bf16
  u16*   hpri  = (u16*)  (ws + 32374784);  // [512,1024] bf16
  unsigned* flags = (unsigned*)(ws + 33423360);  // [64] u32
  // ws end: 33,423,616 bytes

  cvt_weights_k<<<2048, 256, 0, stream>>>(Wsa, Wih, Whh, Wbpri, Wspri, Wbpos,
                                          Wspos, wbase);
  init_carry_k<<<2048, 256, 0, stream>>>(s0, b0, Mp, smask, bbf0, hf, flags);
  kX0<<<256, 512, 0, stream>>>(smask, Af, wsa_b, bsa, xg, Of, wbpos_b, hbO0);

  for (int t = 0; t < NT; ++t) {
    const u16* bprev = (t & 1) ? bbf1 : bbf0;
    u16* bcur = (t & 1) ? bbf0 : bbf1;
    float* hbOc = (t & 1) ? hbO1 : hbO0;
    float* hbOn = (t & 1) ? hbO0 : hbO1;
    kL1<<<160, 512, 0, stream>>>(xg, bprev, wih_b, whh_b, bih, bhh, hf, bcur,
                                 out, hpri, wspri_b, bspri, npri, t);
    kL2<<<384, 512, 0, stream>>>(bcur, wbpos_b, bbpos, hbOc, hbbf,
                                 wbpri_b, bbpri, hpri, Of, hbOn, t);
    kLX<<<192, 512, 0, stream>>>(hbbf, wspos_b, bspos, npos, Mp, out, smask,
                                 Af, wsa_b, bsa, xg,
                                 hpri, wspri_b, bspri, npri, flags, t);
  }
}

// Round 11
// 8208.205 us; speedup vs baseline: 1.9904x; 1.1460x over previous
//
#include <hip/hip_runtime.h>
#include <hip/hip_bf16.h>
#include <math.h>

typedef short bf16x8 __attribute__((ext_vector_type(8)));
typedef float f32x4 __attribute__((ext_vector_type(4)));
typedef unsigned short u16;

#define NT 64
#define NB 512
#define NS 256
#define NA 64
#define NBEL 1024

// d_out element offsets (f32 elements)
#define OUT_B      0
#define OUT_SPRI   33554432
#define OUT_MUPRI  41943040
#define OUT_STDPRI 50331648
#define OUT_SPOS   58720256
#define OUT_MUPOS  67108864
#define OUT_STDPOS 75497472

__device__ __forceinline__ f32x4 mfma16(bf16x8 a, bf16x8 b, f32x4 c) {
  return __builtin_amdgcn_mfma_f32_16x16x32_bf16(a, b, c, 0, 0, 0);
}

__device__ __forceinline__ u16 f2bf(float f) {
  union { float f; unsigned u; } v; v.f = f;
  return (u16)((v.u + 0x7FFFu + ((v.u >> 16) & 1u)) >> 16);
}
__device__ __forceinline__ float bf2f(u16 h) {
  union { unsigned u; float f; } v; v.u = ((unsigned)h) << 16; return v.f;
}

__device__ __forceinline__ bf16x8 ld8bf(const u16* p) { return *(const bf16x8*)p; }

__device__ __forceinline__ bf16x8 cvt8(const float* p) {
  const float4 lo = *(const float4*)p;
  const float4 hi = *(const float4*)(p + 4);
  bf16x8 v;
  v[0] = (short)f2bf(lo.x); v[1] = (short)f2bf(lo.y);
  v[2] = (short)f2bf(lo.z); v[3] = (short)f2bf(lo.w);
  v[4] = (short)f2bf(hi.x); v[5] = (short)f2bf(hi.y);
  v[6] = (short)f2bf(hi.z); v[7] = (short)f2bf(hi.w);
  return v;
}

__device__ __forceinline__ float sigm(float x) { return 1.f / (1.f + __expf(-x)); }
__device__ __forceinline__ float softplus_(float x) {
  if (x > 20.f) return x;
  return log1pf(__expf(x));
}

#define ZACC(acc) { acc[0][0] = (f32x4){0.f,0.f,0.f,0.f}; acc[0][1] = (f32x4){0.f,0.f,0.f,0.f}; \
                    acc[1][0] = (f32x4){0.f,0.f,0.f,0.f}; acc[1][1] = (f32x4){0.f,0.f,0.f,0.f}; }

#define Q4(acc, a0v, a1v, b0v, b1v) \
  acc[0][0] = mfma16(a0v, b0v, acc[0][0]); \
  acc[0][1] = mfma16(a0v, b1v, acc[0][1]); \
  acc[1][0] = mfma16(a1v, b0v, acc[1][0]); \
  acc[1][1] = mfma16(a1v, b1v, acc[1][1]);

__device__ __forceinline__ void gtile(f32x4 (&acc)[2][2],
    const u16* __restrict__ A, int lda, const u16* __restrict__ B, int ldb,
    int K, int r16, int kq) {
  const u16* A0 = A + r16 * lda + kq * 8;
  const u16* A1 = A0 + 16 * lda;
  const u16* B0 = B + (size_t)r16 * ldb + kq * 8;
  const u16* B1 = B0 + 16 * ldb;
#pragma unroll 4
  for (int k = 0; k < K; k += 32) {
    bf16x8 a0 = ld8bf(A0 + k), a1 = ld8bf(A1 + k);
    bf16x8 b0 = ld8bf(B0 + k), b1 = ld8bf(B1 + k);
    Q4(acc, a0, a1, b0, b1);
  }
}
__device__ __forceinline__ void gtileF(f32x4 (&acc)[2][2],
    const float* __restrict__ A, int lda, const u16* __restrict__ B, int ldb,
    int K, int r16, int kq) {
  const float* A0 = A + r16 * lda + kq * 8;
  const float* A1 = A0 + 16 * lda;
  const u16* B0 = B + (size_t)r16 * ldb + kq * 8;
  const u16* B1 = B0 + 16 * ldb;
#pragma unroll 2
  for (int k = 0; k < K; k += 32) {
    bf16x8 a0 = cvt8(A0 + k), a1 = cvt8(A1 + k);
    bf16x8 b0 = ld8bf(B0 + k), b1 = ld8bf(B1 + k);
    Q4(acc, a0, a1, b0, b1);
  }
}

__device__ __forceinline__ void red_write(float* L, f32x4 (&acc)[2][2], int l) {
  const int base = l * 16;
#pragma unroll
  for (int i = 0; i < 2; ++i)
#pragma unroll
    for (int j = 0; j < 2; ++j)
#pragma unroll
      for (int q = 0; q < 4; ++q)
        L[base + (i * 2 + j) * 4 + q] = acc[i][j][q];
}
__device__ __forceinline__ void red_add(const float* L, f32x4 (&acc)[2][2], int l) {
  const int base = l * 16;
#pragma unroll
  for (int i = 0; i < 2; ++i)
#pragma unroll
    for (int j = 0; j < 2; ++j)
#pragma unroll
      for (int q = 0; q < 4; ++q)
        acc[i][j][q] += L[base + (i * 2 + j) * 4 + q];
}

// -------- device-scope flag sync (proven R7/R8/R10) --------
__device__ __forceinline__ void setflag_blk(unsigned* f) {
  __syncthreads();
  if (threadIdx.x == 0)
    __hip_atomic_fetch_add(f, 1u, __ATOMIC_RELEASE, __HIP_MEMORY_SCOPE_AGENT);
}
__device__ __forceinline__ void waitflag_blk(unsigned* f, unsigned target) {
  if (threadIdx.x == 0) {
    while (__hip_atomic_load(f, __ATOMIC_RELAXED, __HIP_MEMORY_SCOPE_AGENT) < target)
      __builtin_amdgcn_s_sleep(2);
    (void)__hip_atomic_load(f, __ATOMIC_ACQUIRE, __HIP_MEMORY_SCOPE_AGENT);
  }
  __syncthreads();
}

// -------- P0: weights f32 -> bf16 --------
__global__ __launch_bounds__(256) void cvt_weights_k(
    const float* __restrict__ wsa, const float* __restrict__ wih,
    const float* __restrict__ whh, const float* __restrict__ wbpri,
    const float* __restrict__ wspri, const float* __restrict__ wbpos,
    const float* __restrict__ wspos, u16* __restrict__ dst) {
  const int S0 = 327680;
  const int S1 = S0 + 3145728;
  const int S2 = S1 + 3145728;
  const int S3 = S2 + 1048576;
  const int S4 = S3 + 524288;
  const int S5 = S4 + 2097152;
  const int S6 = S5 + 524288;
  for (int i = blockIdx.x * blockDim.x + threadIdx.x; i < S6;
       i += gridDim.x * blockDim.x) {
    float v;
    if (i < S0) v = wsa[i];
    else if (i < S1) v = wih[i - S0];
    else if (i < S2) v = whh[i - S1];
    else if (i < S3) v = wbpri[i - S2];
    else if (i < S4) v = wspri[i - S3];
    else if (i < S5) v = wbpos[i - S4];
    else v = wspos[i - S5];
    dst[i] = f2bf(v);
  }
}

// -------- P1: init carries + zero flags --------
__global__ __launch_bounds__(256) void init_carry_k(
    const float* __restrict__ s0, const float* __restrict__ b0,
    const float* __restrict__ Mptr, u16* __restrict__ smask,
    u16* __restrict__ bbf, float* __restrict__ hf,
    unsigned* __restrict__ flags) {
  for (int i = blockIdx.x * blockDim.x + threadIdx.x; i < NB * NBEL;
       i += gridDim.x * blockDim.x) {
    float b = b0[i];
    bbf[i] = f2bf(b);
    hf[i] = b;
    if (i < NB * NS) {
      int row = i >> 8;
      smask[i] = f2bf(s0[i] * Mptr[row]);
    }
    if (i < 3 * NT) flags[i] = 0;
  }
}

// -------- device pieces --------

// spri: 32 blocks (8 x 4), K-split 8-wave
__device__ __forceinline__ void dev_spri(
    int g, int wid, int kh, int r16, int kq, int l, int tt,
    const u16* __restrict__ hpri, const u16* __restrict__ wspri,
    const float* __restrict__ bspri, const float* __restrict__ npri,
    float* __restrict__ out, float* lred0, float* lred1) {
  const int bm = g >> 2, bn = g & 3;
  const int row0 = bm * 64 + (wid >> 1) * 32;
  const int c0 = bn * 64 + (wid & 1) * 32;
  f32x4 am[2][2], ah[2][2];
  ZACC(am); ZACC(ah);
  const u16* A0 = hpri + (row0 + r16) * NBEL + kh * 512 + kq * 8;
  const u16* A1 = A0 + 16 * NBEL;
  const u16* Bm0 = wspri + (size_t)(c0 + r16) * NBEL + kh * 512 + kq * 8;
  const u16* Bm1 = Bm0 + 16 * NBEL;
  const u16* Bh0 = wspri + (size_t)(c0 + 256 + r16) * NBEL + kh * 512 + kq * 8;
  const u16* Bh1 = Bh0 + 16 * NBEL;
#pragma unroll 4
  for (int k = 0; k < 512; k += 32) {
    bf16x8 a0 = ld8bf(A0 + k), a1 = ld8bf(A1 + k);
    bf16x8 m0 = ld8bf(Bm0 + k), m1 = ld8bf(Bm1 + k);
    Q4(am, a0, a1, m0, m1);
    bf16x8 h0 = ld8bf(Bh0 + k), h1 = ld8bf(Bh1 + k);
    Q4(ah, a0, a1, h0, h1);
  }
  if (kh == 1) {
    red_write(lred0, am, l);
    red_write(lred1, ah, l);
  }
  __syncthreads();
  if (kh == 0) {
    red_add(lred0, am, l);
    red_add(lred1, ah, l);
#pragma unroll
    for (int i = 0; i < 2; ++i)
#pragma unroll
      for (int j = 0; j < 2; ++j)
#pragma unroll
        for (int q = 0; q < 4; ++q) {
          const int row = row0 + i * 16 + kq * 4 + q;
          const int c = c0 + j * 16 + r16;
          const size_t idx = (size_t)tt * (NB * NS) + (size_t)row * NS + c;
          const float mu = am[i][j][q] + bspri[c];
          const float hp = ah[i][j][q] + bspri[c + 256];
          const float sd = softplus_(hp) + 0.1f;
          out[OUT_SPRI + idx] = mu + sd * npri[idx];
          out[OUT_MUPRI + idx] = mu;
          out[OUT_STDPRI + idx] = sd;
        }
  }
}

// x: 64 blocks (8 x 8), 8-wave full-K 64x128 tiles
__device__ __forceinline__ void dev_x64(
    int g, int wid8, int r16, int kq, int t,
    const u16* __restrict__ smask, const float* __restrict__ Af,
    const u16* __restrict__ wsa, const float* __restrict__ bsa,
    u16* __restrict__ xg) {
  const int row0 = (g >> 3) * 64 + (wid8 >> 2) * 32;
  const int col0 = (g & 7) * 128 + (wid8 & 3) * 32;
  f32x4 acc[2][2]; ZACC(acc);
  gtile(acc, smask + row0 * NS, NS, wsa + (size_t)col0 * 320, 320, 256, r16, kq);
  gtileF(acc, Af + (size_t)t * (NB * NA) + (size_t)row0 * NA, NA,
         wsa + (size_t)col0 * 320 + 256, 320, 64, r16, kq);
#pragma unroll
  for (int i = 0; i < 2; ++i)
#pragma unroll
    for (int j = 0; j < 2; ++j)
#pragma unroll
      for (int q = 0; q < 4; ++q) {
        const int row = row0 + i * 16 + kq * 4 + q;
        const int col = col0 + j * 16 + r16;
        xg[row * NBEL + col] = f2bf(fmaxf(acc[i][j][q] + bsa[col], 0.f));
      }
}

// hbO: 64 blocks (8 x 8), 8-wave full-K 64x128 tiles (f32 A)
__device__ __forceinline__ void dev_hbO64(
    int g, int wid8, int r16, int kq,
    const float* __restrict__ OfT, const u16* __restrict__ wbpos,
    float* __restrict__ hbOn) {
  const int row0 = (g >> 3) * 64 + (wid8 >> 2) * 32;
  const int col0 = (g & 7) * 128 + (wid8 & 3) * 32;
  f32x4 acc[2][2]; ZACC(acc);
  gtileF(acc, OfT + (size_t)row0 * NBEL, NBEL,
         wbpos + (size_t)col0 * 2048 + 1024, 2048, 1024, r16, kq);
#pragma unroll
  for (int i = 0; i < 2; ++i)
#pragma unroll
    for (int j = 0; j < 2; ++j)
#pragma unroll
      for (int q = 0; q < 4; ++q) {
        const int row = row0 + i * 16 + kq * 4 + q;
        const int col = col0 + j * 16 + r16;
        hbOn[row * NBEL + col] = acc[i][j][q];
      }
}

// gh: 96 blocks (8 x 12), 8-wave, two 64x128 passes -> 64x256 tile, bf16 out
__device__ __forceinline__ void dev_gh96(
    int g, int wid8, int r16, int kq,
    const u16* __restrict__ bsrc, const u16* __restrict__ whh,
    const float* __restrict__ bhh, u16* __restrict__ ghn) {
  const int bm = g / 12, bc = g % 12;
  const int row0 = bm * 64 + (wid8 >> 2) * 32;
#pragma unroll
  for (int jt = 0; jt < 2; ++jt) {
    const int col0 = bc * 256 + (wid8 & 3) * 32 + jt * 128;
    f32x4 acc[2][2]; ZACC(acc);
    gtile(acc, bsrc + row0 * NBEL, NBEL, whh + (size_t)col0 * NBEL, NBEL,
          1024, r16, kq);
#pragma unroll
    for (int i = 0; i < 2; ++i)
#pragma unroll
      for (int j = 0; j < 2; ++j)
#pragma unroll
        for (int q = 0; q < 4; ++q) {
          const int row = row0 + i * 16 + kq * 4 + q;
          const int col = col0 + j * 16 + r16;
          ghn[row * 3072 + col] = f2bf(acc[i][j][q] + bhh[col]);
        }
  }
}

// bpri: 64 blocks (8 x 8), 8-wave full-K
__device__ __forceinline__ void dev_bpri64(
    int g, int wid8, int r16, int kq,
    const u16* __restrict__ bcur, const u16* __restrict__ wbpri,
    const float* __restrict__ bbpri, u16* __restrict__ hpri) {
  const int row0 = (g >> 3) * 64 + (wid8 >> 2) * 32;
  const int col0 = (g & 7) * 128 + (wid8 & 3) * 32;
  f32x4 acc[2][2]; ZACC(acc);
  gtile(acc, bcur + row0 * NBEL, NBEL, wbpri + (size_t)col0 * NBEL, NBEL,
        1024, r16, kq);
#pragma unroll
  for (int i = 0; i < 2; ++i)
#pragma unroll
    for (int j = 0; j < 2; ++j)
#pragma unroll
      for (int q = 0; q < 4; ++q) {
        const int row = row0 + i * 16 + kq * 4 + q;
        const int col = col0 + j * 16 + r16;
        hpri[row * NBEL + col] = f2bf(fmaxf(acc[i][j][q] + bbpri[col], 0.f));
      }
}

// ======================= kX0: x(0) [0..63] | hbO(0) [64..127] | gh(0) [128..223] =======================
__global__ __launch_bounds__(512, 2) void kX0(
    const u16* __restrict__ smask, const float* __restrict__ Af,
    const u16* __restrict__ wsa, const float* __restrict__ bsa,
    u16* __restrict__ xg, const float* __restrict__ Of,
    const u16* __restrict__ wbpos, float* __restrict__ hbO0,
    const u16* __restrict__ bbf, const u16* __restrict__ whh,
    const float* __restrict__ bhh, u16* __restrict__ ghA) {
  const int l = threadIdx.x & 63, r16 = l & 15, kq = l >> 4;
  const int wid8 = threadIdx.x >> 6;
  if (blockIdx.x < 64) {
    dev_x64(blockIdx.x, wid8, r16, kq, 0, smask, Af, wsa, bsa, xg);
  } else if (blockIdx.x < 128) {
    dev_hbO64(blockIdx.x - 64, wid8, r16, kq, Of, wbpos, hbO0);
  } else {
    dev_gh96(blockIdx.x - 128, wid8, r16, kq, bbf, whh, bhh, ghA);
  }
}

// ======================= kG: gi+GRU [0..127] | spri(t-1) [128..159] =======================
__global__ __launch_bounds__(512, 2) void kG(
    const u16* __restrict__ xg, const u16* __restrict__ wih,
    const float* __restrict__ bih, const u16* __restrict__ ghc,
    float* __restrict__ hf, u16* __restrict__ bcur, float* __restrict__ out,
    const u16* __restrict__ hpri, const u16* __restrict__ wspri,
    const float* __restrict__ bspri, const float* __restrict__ npri, int t) {
  __shared__ float lred[4][3][1024];  // 48KB
  const int l = threadIdx.x & 63, r16 = l & 15, kq = l >> 4;
  const int wid8 = threadIdx.x >> 6;
  const int wid = wid8 & 3, kh = wid8 >> 2;
  if (blockIdx.x < 128) {
    const int g = blockIdx.x, bm = g >> 4, bn = g & 15;
    const int row0 = bm * 64 + (wid >> 1) * 32;
    const int col0 = bn * 64 + (wid & 1) * 32;
    f32x4 ar[2][2], az[2][2], an[2][2];
    ZACC(ar); ZACC(az); ZACC(an);
    const u16* A0 = xg + (row0 + r16) * NBEL + kh * 512 + kq * 8;
    const u16* A1 = A0 + 16 * NBEL;
    const u16* Br0 = wih + (size_t)(col0 + r16) * NBEL + kh * 512 + kq * 8;
    const u16* Br1 = Br0 + 16 * NBEL;
    const u16* Bz0 = wih + (size_t)(col0 + 1024 + r16) * NBEL + kh * 512 + kq * 8;
    const u16* Bz1 = Bz0 + 16 * NBEL;
    const u16* Bn0 = wih + (size_t)(col0 + 2048 + r16) * NBEL + kh * 512 + kq * 8;
    const u16* Bn1 = Bn0 + 16 * NBEL;
#pragma unroll 4
    for (int k = 0; k < 512; k += 32) {
      bf16x8 a0 = ld8bf(A0 + k), a1 = ld8bf(A1 + k);
      bf16x8 b0 = ld8bf(Br0 + k), b1 = ld8bf(Br1 + k);
      Q4(ar, a0, a1, b0, b1);
      bf16x8 c0 = ld8bf(Bz0 + k), c1 = ld8bf(Bz1 + k);
      Q4(az, a0, a1, c0, c1);
      bf16x8 d0 = ld8bf(Bn0 + k), d1 = ld8bf(Bn1 + k);
      Q4(an, a0, a1, d0, d1);
    }
    if (kh == 1) {
      red_write(&lred[wid][0][0], ar, l);
      red_write(&lred[wid][1][0], az, l);
      red_write(&lred[wid][2][0], an, l);
    }
    __syncthreads();
    if (kh == 0) {
      const int base = l * 16;
#pragma unroll
      for (int i = 0; i < 2; ++i)
#pragma unroll
        for (int j = 0; j < 2; ++j)
#pragma unroll
          for (int q = 0; q < 4; ++q) {
            const int row = row0 + i * 16 + kq * 4 + q;
            const int c = col0 + j * 16 + r16;
            const int li = base + (i * 2 + j) * 4 + q;
            const u16* ghrow = ghc + row * 3072;
            const float r = sigm(ar[i][j][q] + lred[wid][0][li] + bih[c] +
                                 bf2f(ghrow[c]));
            const float z = sigm(az[i][j][q] + lred[wid][1][li] + bih[c + 1024] +
                                 bf2f(ghrow[c + 1024]));
            const float n = tanhf(an[i][j][q] + lred[wid][2][li] + bih[c + 2048] +
                                  r * bf2f(ghrow[c + 2048]));
            const float h = hf[row * NBEL + c];
            const float bnew = (1.f - z) * n + z * h;
            hf[row * NBEL + c] = bnew;
            bcur[row * NBEL + c] = f2bf(bnew);
            out[OUT_B + (size_t)t * (NB * NBEL) + row * NBEL + c] = bnew;
          }
    }
  } else if (t >= 1) {
    dev_spri(blockIdx.x - 128, wid, kh, r16, kq, l, t - 1,
             hpri, wspri, bspri, npri, out,
             &lred[wid][0][0], &lred[wid][1][0]);
  }
}

// ======================= kM: hbB [0..127] | bpri [128..191] | gh(t+1) [192..287]
//                         | hbO(t+1) [288..351] | spos [352..383] | x(t+1) [384..447]
//                         | spri(63) [448..479] =======================
__global__ __launch_bounds__(512, 2) void kM(
    const u16* __restrict__ bcur, const u16* __restrict__ wbpos,
    const float* __restrict__ bbpos, const float* __restrict__ hbOc,
    u16* __restrict__ hbbf,
    const u16* __restrict__ wbpri, const float* __restrict__ bbpri,
    u16* __restrict__ hpri,
    const u16* __restrict__ whh, const float* __restrict__ bhh,
    u16* __restrict__ ghn,
    const float* __restrict__ Of, float* __restrict__ hbOn,
    const u16* __restrict__ wspos, const float* __restrict__ bspos,
    const float* __restrict__ npos, const float* __restrict__ Mptr,
    u16* __restrict__ smask,
    const float* __restrict__ Af, const u16* __restrict__ wsa,
    const float* __restrict__ bsa, u16* __restrict__ xg,
    const u16* __restrict__ wspri, const float* __restrict__ bspri,
    const float* __restrict__ npri,
    float* __restrict__ out,
    unsigned* __restrict__ fH, unsigned* __restrict__ fS,
    unsigned* __restrict__ fB, int t) {
  __shared__ float lred[4][2][1024];  // 32KB
  const int l = threadIdx.x & 63, r16 = l & 15, kq = l >> 4;
  const int wid8 = threadIdx.x >> 6;
  const int wid = wid8 & 3, kh = wid8 >> 2;
  if (blockIdx.x < 128) {
    // ---- hbB(t): K-split 8-wave ----
    const int g = blockIdx.x, bm = g >> 4, bn = g & 15;
    const int row0 = bm * 64 + (wid >> 1) * 32;
    const int col0 = bn * 64 + (wid & 1) * 32;
    f32x4 acc[2][2]; ZACC(acc);
    const u16* A0 = bcur + (row0 + r16) * NBEL + kh * 512 + kq * 8;
    const u16* A1 = A0 + 16 * NBEL;
    const u16* B0 = wbpos + (size_t)(col0 + r16) * 2048 + kh * 512 + kq * 8;
    const u16* B1 = B0 + 16 * 2048;
#pragma unroll 4
    for (int k = 0; k < 512; k += 32) {
      bf16x8 a0 = ld8bf(A0 + k), a1 = ld8bf(A1 + k);
      bf16x8 b0 = ld8bf(B0 + k), b1 = ld8bf(B1 + k);
      Q4(acc, a0, a1, b0, b1);
    }
    if (kh == 1) red_write(&lred[wid][0][0], acc, l);
    __syncthreads();
    if (kh == 0) {
      red_add(&lred[wid][0][0], acc, l);
#pragma unroll
      for (int i = 0; i < 2; ++i)
#pragma unroll
        for (int j = 0; j < 2; ++j)
#pragma unroll
          for (int q = 0; q < 4; ++q) {
            const int row = row0 + i * 16 + kq * 4 + q;
            const int col = col0 + j * 16 + r16;
            const float v = acc[i][j][q] + hbOc[row * NBEL + col] + bbpos[col];
            hbbf[row * NBEL + col] = f2bf(fmaxf(v, 0.f));
          }
    }
    setflag_blk(&fH[t]);
  } else if (blockIdx.x < 192) {
    dev_bpri64(blockIdx.x - 128, wid8, r16, kq, bcur, wbpri, bbpri, hpri);
    setflag_blk(&fB[t]);
  } else if (blockIdx.x < 288) {
    if (t + 1 >= NT) return;
    dev_gh96(blockIdx.x - 192, wid8, r16, kq, bcur, whh, bhh, ghn);
  } else if (blockIdx.x < 352) {
    if (t + 1 >= NT) return;
    dev_hbO64(blockIdx.x - 288, wid8, r16, kq,
              Of + (size_t)(t + 1) * (NB * NBEL), wbpos, hbOn);
  } else if (blockIdx.x < 384) {
    // ---- spos(t): wait for all hbB blocks ----
    waitflag_blk(&fH[t], 128);
    const int g = blockIdx.x - 352, bm = g >> 2, bn = g & 3;
    const int row0 = bm * 64 + (wid >> 1) * 32;
    const int c0 = bn * 64 + (wid & 1) * 32;
    f32x4 am[2][2], ah[2][2];
    ZACC(am); ZACC(ah);
    const u16* A0 = hbbf + (row0 + r16) * NBEL + kh * 512 + kq * 8;
    const u16* A1 = A0 + 16 * NBEL;
    const u16* Bm0 = wspos + (size_t)(c0 + r16) * NBEL + kh * 512 + kq * 8;
    const u16* Bm1 = Bm0 + 16 * NBEL;
    const u16* Bh0 = wspos + (size_t)(c0 + 256 + r16) * NBEL + kh * 512 + kq * 8;
    const u16* Bh1 = Bh0 + 16 * NBEL;
#pragma unroll 4
    for (int k = 0; k < 512; k += 32) {
      bf16x8 a0 = ld8bf(A0 + k), a1 = ld8bf(A1 + k);
      bf16x8 m0 = ld8bf(Bm0 + k), m1 = ld8bf(Bm1 + k);
      Q4(am, a0, a1, m0, m1);
      bf16x8 h0 = ld8bf(Bh0 + k), h1 = ld8bf(Bh1 + k);
      Q4(ah, a0, a1, h0, h1);
    }
    if (kh == 1) {
      red_write(&lred[wid][0][0], am, l);
      red_write(&lred[wid][1][0], ah, l);
    }
    __syncthreads();
    if (kh == 0) {
      red_add(&lred[wid][0][0], am, l);
      red_add(&lred[wid][1][0], ah, l);
#pragma unroll
      for (int i = 0; i < 2; ++i)
#pragma unroll
        for (int j = 0; j < 2; ++j)
#pragma unroll
          for (int q = 0; q < 4; ++q) {
            const int row = row0 + i * 16 + kq * 4 + q;
            const int c = c0 + j * 16 + r16;
            const float mu = am[i][j][q] + bspos[c];
            const float hq = ah[i][j][q] + bspos[c + 256];
            const float sd = softplus_(hq) + 0.1f;
            const size_t idx = (size_t)t * (NB * NS) + (size_t)row * NS + c;
            const float sq = mu + sd * npos[idx];
            out[OUT_SPOS + idx] = sq;
            out[OUT_MUPOS + idx] = mu;
            out[OUT_STDPOS + idx] = sd;
            const float mn = (t < NT - 1) ? Mptr[(t + 1) * NB + row] : 1.f;
            smask[row * NS + c] = f2bf(sq * mn);
          }
    }
    setflag_blk(&fS[t]);
  } else if (blockIdx.x < 448) {
    // ---- x(t+1): wait for spos ----
    if (t + 1 >= NT) return;
    waitflag_blk(&fS[t], 32);
    dev_x64(blockIdx.x - 384, wid8, r16, kq, t + 1, smask, Af, wsa, bsa, xg);
  } else {
    // ---- spri(63) at the final step: wait for bpri(63) ----
    if (t != NT - 1) return;
    waitflag_blk(&fB[t], 64);
    dev_spri(blockIdx.x - 448, wid, kh, r16, kq, l, t,
             hpri, wspri, bspri, npri, out,
             &lred[wid][0][0], &lred[wid][1][0]);
  }
}

extern "C" void kernel_launch(void* const* d_in, const int* in_sizes, int n_in,
                              void* d_out, int out_size, void* d_ws, size_t ws_size,
                              hipStream_t stream) {
  const float* s0 = (const float*)d_in[0];
  const float* Af = (const float*)d_in[1];
  const float* b0 = (const float*)d_in[2];
  const float* Of = (const float*)d_in[3];
  const float* Mp = (const float*)d_in[4];
  const float* npri = (const float*)d_in[5];
  const float* npos = (const float*)d_in[6];
  const float* Wsa = (const float*)d_in[7];
  const float* bsa = (const float*)d_in[8];
  const float* Wih = (const float*)d_in[9];
  const float* bih = (const float*)d_in[10];
  const float* Whh = (const float*)d_in[11];
  const float* bhh = (const float*)d_in[12];
  const float* Wbpri = (const float*)d_in[13];
  const float* bbpri = (const float*)d_in[14];
  const float* Wspri = (const float*)d_in[15];
  const float* bspri = (const float*)d_in[16];
  const float* Wbpos = (const float*)d_in[17];
  const float* bbpos = (const float*)d_in[18];
  const float* Wspos = (const float*)d_in[19];
  const float* bspos = (const float*)d_in[20];

  float* out = (float*)d_out;
  char* ws = (char*)d_ws;
  u16* wbase   = (u16*)ws;
  u16* wsa_b   = wbase;
  u16* wih_b   = wbase + 327680;
  u16* whh_b   = wbase + 3473408;
  u16* wbpri_b = wbase + 6619136;
  u16* wspri_b = wbase + 7667712;
  u16* wbpos_b = wbase + 8192000;
  u16* wspos_b = wbase + 10289152;
  // weights end at byte 21,626,880
  u16*   smask = (u16*)  (ws + 21626880);  // [512,256]  bf16
  u16*   bbf   = (u16*)  (ws + 21889024);  // [512,1024] bf16 (single buffer)
  float* hf    = (float*)(ws + 22937600);  // [512,1024] f32
  u16*   xg    = (u16*)  (ws + 25034752);  // [512,1024] bf16
  float* hbO0  = (float*)(ws + 26083328);  // [512,1024] f32
  float* hbO1  = (float*)(ws + 28180480);  // [512,1024] f32
  u16*   hbbf  = (u16*)  (ws + 30277632);  // [512,1024] bf16
  u16*   hpri  = (u16*)  (ws + 31326208);  // [512,1024] bf16
  u16*   ghA   = (u16*)  (ws + 32374784);  // [512,3072] bf16 3MB
  u16*   ghB   = (u16*)  (ws + 35520512);  // [512,3072] bf16 3MB
  unsigned* flags = (unsigned*)(ws + 38666240);  // [3*64] u32
  unsigned* fH = flags, *fS = flags + NT, *fB = flags + 2 * NT;
  // ws end: ~38.7MB

  cvt_weights_k<<<2048, 256, 0, stream>>>(Wsa, Wih, Whh, Wbpri, Wspri, Wbpos,
                                          Wspos, wbase);
  init_carry_k<<<2048, 256, 0, stream>>>(s0, b0, Mp, smask, bbf, hf, flags);
  kX0<<<224, 512, 0, stream>>>(smask, Af, wsa_b, bsa, xg, Of, wbpos_b, hbO0,
                               bbf, whh_b, bhh, ghA);

  for (int t = 0; t < NT; ++t) {
    float* hbOc = (t & 1) ? hbO1 : hbO0;
    float* hbOn = (t & 1) ? hbO0 : hbO1;
    u16* ghc = (t & 1) ? ghB : ghA;
    u16* ghn = (t & 1) ? ghA : ghB;
    kG<<<160, 512, 0, stream>>>(xg, wih_b, bih, ghc, hf, bbf, out,
                                hpri, wspri_b, bspri, npri, t);
    kM<<<480, 512, 0, stream>>>(bbf, wbpos_b, bbpos, hbOc, hbbf,
                                wbpri_b, bbpri, hpri,
                                whh_b, bhh, ghn,
                                Of, hbOn,
                                wspos_b, bspos, npos, Mp, smask,
                                Af, wsa_b, bsa, xg,
                                wspri_b, bspri, npri,
                                out, fH, fS, fB, t);
  }
}